// Round 7
// baseline (3858.414 us; speedup 1.0000x reference)
//
#include <hip/hip_runtime.h>

// ---------------- types / helpers ----------------
typedef short bh8 __attribute__((ext_vector_type(8)));     // 8 x bf16 raw
typedef float f32x4 __attribute__((ext_vector_type(4)));

#define DEVI __device__ __forceinline__

union U8 { bh8 v; unsigned short u[8]; };

DEVI float bf2f(unsigned short u){
  unsigned int x = ((unsigned int)u) << 16;
  return __builtin_bit_cast(float, x);
}
DEVI unsigned short f2bf(float f){
  unsigned int u = __builtin_bit_cast(unsigned int, f);
  u += 0x7fffu + ((u >> 16) & 1u);
  return (unsigned short)(u >> 16);
}
DEVI float sigm(float x){ return 1.0f/(1.0f + __expf(-x)); }

DEVI f32x4 MFMA(bh8 a, bh8 b, f32x4 c){
  return __builtin_amdgcn_mfma_f32_16x16x32_bf16(a, b, c, 0, 0, 0);
}

// ---------------- prep kernels ----------------
__global__ void k_gather_src(const int* seq, const float* emb, unsigned short* dst){
  int m = blockIdx.x;                 // 0..2047  (b*128+s)
  int idx = seq[m];
  const float* s = emb + (size_t)idx * 256;
  unsigned short* d = dst + (size_t)m * 256;
  for (int e = threadIdx.x; e < 256; e += 64) d[e] = f2bf(s[e]);
}

__global__ void k_gather_tok(const int* tseq, const float* emb, unsigned short* dst){
  int m = blockIdx.x;                 // 0..1023 (b*63+t)
  unsigned short* d = dst + (size_t)m * 256;
  if (m < 1008){
    int b = m / 63, t = m - b * 63;
    int idx = tseq[b * 64 + t];
    const float* s = emb + (size_t)idx * 256;
    for (int e = threadIdx.x; e < 256; e += 64) d[e] = f2bf(s[e]);
  } else {
    for (int e = threadIdx.x; e < 256; e += 64) d[e] = 0;
  }
}

// strided fp32 -> bf16 convert; dst rows of 256, src row stride = rstride
__global__ void k_conv(const float* src, unsigned short* dst, int rows, int rstride){
  size_t n = (size_t)rows * 128;      // pairs
  for (size_t i = (size_t)blockIdx.x * 256 + threadIdx.x; i < n; i += (size_t)gridDim.x * 256){
    size_t r = i >> 7; int c = ((int)(i & 127)) * 2;
    const float* s = src + r * (size_t)rstride + c;
    unsigned int hp = (unsigned int)f2bf(s[0]) | ((unsigned int)f2bf(s[1]) << 16);
    *(unsigned int*)(dst + r * 256 + c) = hp;
  }
}

__global__ void k_fold(const float* A, int offA, int sAm, int sAk,
                       const float* Bm, int offB, int sBn, int sBk,
                       const float* addM, float* Cf, unsigned short* Cb,
                       int M, int N){
  int i = blockIdx.x * 256 + threadIdx.x;
  if (i >= M * N) return;
  int m = i / N, n = i - m * N;
  const float* a = A + offA + (size_t)m * sAm;
  const float* b = Bm + offB + (size_t)n * sBn;
  float acc = 0.f;
  for (int k = 0; k < 256; ++k) acc += a[(size_t)k * sAk] * b[(size_t)k * sBk];
  if (addM) acc += addM[m];
  if (Cf) Cf[i] = acc;
  if (Cb) Cb[i] = f2bf(acc);
}

__global__ void k_sb(const unsigned short* enc, const float* c4, const float* c5, float* sb){
  int m = blockIdx.x * 256 + threadIdx.x;
  if (m >= 2048) return;
  const unsigned short* e = enc + (size_t)m * 256;
  float a = 0.f;
  for (int k = 0; k < 256; ++k) a += bf2f(e[k]) * c4[k];
  sb[m] = a + c5[0];
}

// ---------------- bf16 MFMA GEMM, K=256 fixed (verified) ----------------
__global__ __launch_bounds__(256) void k_gemm(const unsigned short* __restrict__ A,
      const unsigned short* __restrict__ Bw, const float* __restrict__ bias,
      float* __restrict__ Cf, unsigned short* __restrict__ Cb, int Mlog, int N){
  __shared__ __align__(16) unsigned short lA[128 * 32];
  __shared__ __align__(16) unsigned short lB[128 * 32];
  int tid = threadIdx.x;
  int lane = tid & 63, wave = tid >> 6;
  int wm = wave >> 1, wn = wave & 1;
  int kg = lane >> 4, l15 = lane & 15;
  size_t tm = blockIdx.y, tn = blockIdx.x;
  f32x4 acc[4][4];
#pragma unroll
  for (int i = 0; i < 4; ++i)
#pragma unroll
    for (int j = 0; j < 4; ++j) acc[i][j] = (f32x4){0.f, 0.f, 0.f, 0.f};

  for (int ks = 0; ks < 8; ++ks){
    __syncthreads();
#pragma unroll
    for (int i = 0; i < 2; ++i){
      int slot = i * 256 + tid;
      int r = slot >> 2, sg = slot & 3;
      bh8 va = *reinterpret_cast<const bh8*>(A + (tm * 128 + r) * 256 + ks * 32 + sg * 8);
      *reinterpret_cast<bh8*>((char*)lA + r * 64 + ((sg ^ (r & 3)) << 4)) = va;
      bh8 vb = *reinterpret_cast<const bh8*>(Bw + (tn * 128 + r) * 256 + ks * 32 + sg * 8);
      *reinterpret_cast<bh8*>((char*)lB + r * 64 + ((sg ^ (r & 3)) << 4)) = vb;
    }
    __syncthreads();
    bh8 af[4], bfr[4];
#pragma unroll
    for (int mi = 0; mi < 4; ++mi){
      int r = wm * 64 + mi * 16 + l15;
      af[mi] = *reinterpret_cast<const bh8*>((char*)lA + r * 64 + ((kg ^ (r & 3)) << 4));
    }
#pragma unroll
    for (int ni = 0; ni < 4; ++ni){
      int r = wn * 64 + ni * 16 + l15;
      bfr[ni] = *reinterpret_cast<const bh8*>((char*)lB + r * 64 + ((kg ^ (r & 3)) << 4));
    }
#pragma unroll
    for (int mi = 0; mi < 4; ++mi)
#pragma unroll
      for (int ni = 0; ni < 4; ++ni)
        acc[mi][ni] = MFMA(af[mi], bfr[ni], acc[mi][ni]);
  }
#pragma unroll
  for (int ni = 0; ni < 4; ++ni){
    int col = (int)tn * 128 + wn * 64 + ni * 16 + l15;
    float bv = bias ? bias[col] : 0.f;
#pragma unroll
    for (int mi = 0; mi < 4; ++mi){
#pragma unroll
      for (int rg = 0; rg < 4; ++rg){
        int row = (int)tm * 128 + wm * 64 + mi * 16 + kg * 4 + rg;
        if (row < Mlog){
          float v = acc[mi][ni][rg] + bv;
          if (Cb) Cb[(size_t)row * N + col] = f2bf(v);
          else    Cf[(size_t)row * N + col] = v;
        }
      }
    }
  }
}

// ---------------- block=batch encoder: no cross-block sync ----------------
// 16 blocks x 1024 threads; thread = gate row; Whh streamed bf16 from L2.
__global__ __launch_bounds__(1024) void k_enc_b(const unsigned short* __restrict__ Whh_bf,
      const float* __restrict__ Xg, unsigned short* __restrict__ enc_bf,
      float* __restrict__ hfin, float* __restrict__ cfin){
  __shared__ __align__(16) float h_l[256];
  __shared__ float c_l[256];
  __shared__ float g_l[1024];
  int tid = threadIdx.x, b = blockIdx.x;
  if (tid < 256){ h_l[tid] = 0.f; c_l[tid] = 0.f; }
  __syncthreads();
  const unsigned short* wr = Whh_bf + (size_t)tid * 256;
  for (int t = 0; t < 128; ++t){
    float acc = Xg[(size_t)(b * 128 + t) * 1024 + tid];
#pragma unroll
    for (int k16 = 0; k16 < 16; ++k16){
      float4 h0 = *(const float4*)(h_l + k16 * 16);       // wave-uniform broadcast
      float4 h1 = *(const float4*)(h_l + k16 * 16 + 4);
      float4 h2 = *(const float4*)(h_l + k16 * 16 + 8);
      float4 h3 = *(const float4*)(h_l + k16 * 16 + 12);
      U8 w0, w1; 
      w0.v = *reinterpret_cast<const bh8*>(wr + k16 * 16);
      w1.v = *reinterpret_cast<const bh8*>(wr + k16 * 16 + 8);
      acc += h0.x*bf2f(w0.u[0]) + h0.y*bf2f(w0.u[1]) + h0.z*bf2f(w0.u[2]) + h0.w*bf2f(w0.u[3]);
      acc += h1.x*bf2f(w0.u[4]) + h1.y*bf2f(w0.u[5]) + h1.z*bf2f(w0.u[6]) + h1.w*bf2f(w0.u[7]);
      acc += h2.x*bf2f(w1.u[0]) + h2.y*bf2f(w1.u[1]) + h2.z*bf2f(w1.u[2]) + h2.w*bf2f(w1.u[3]);
      acc += h3.x*bf2f(w1.u[4]) + h3.y*bf2f(w1.u[5]) + h3.z*bf2f(w1.u[6]) + h3.w*bf2f(w1.u[7]);
    }
    g_l[tid] = acc;
    __syncthreads();
    if (tid < 256){
      float gi = g_l[tid], gf = g_l[256 + tid], gg = g_l[512 + tid], go = g_l[768 + tid];
      float c = sigm(gf) * c_l[tid] + sigm(gi) * tanhf(gg);
      float h = sigm(go) * tanhf(c);
      c_l[tid] = c; h_l[tid] = h;
      enc_bf[(size_t)(b * 128 + t) * 256 + tid] = f2bf(h);
    }
    __syncthreads();
  }
  if (tid < 256){ hfin[b * 256 + tid] = h_l[tid]; cfin[b * 256 + tid] = c_l[tid]; }
}

// ---------------- block=batch decoder: no cross-block sync ----------------
// 16 blocks x 1024 threads. KW LDS-resident (swizzled); VWWT contiguous rows.
__global__ __launch_bounds__(1024) void k_dec_b(const unsigned short* __restrict__ Whh_bf,
      const float* __restrict__ Xd, const unsigned short* __restrict__ KW,
      const unsigned short* __restrict__ VWWT, const float* __restrict__ sb,
      const float* __restrict__ hfin, const float* __restrict__ cfin,
      unsigned short* __restrict__ Hs){
  __shared__ __align__(16) unsigned short kw_l[128 * 256];   // 64 KB, chunk-XOR swizzled
  __shared__ __align__(16) float h_l[256];
  __shared__ float c_l[256];
  __shared__ float g_l[1024];
  __shared__ float sc_l[128];
  __shared__ float at_l[128];
  __shared__ float red0, red1;
  int tid = threadIdx.x, b = blockIdx.x;

  // stage KW[b] into LDS, 16B chunks XOR-swizzled: logical chunk c of row -> slot c^(row&31)
#pragma unroll
  for (int i = 0; i < 4; ++i){
    int id = i * 1024 + tid;
    int row = id >> 5, c = id & 31;
    bh8 v = *reinterpret_cast<const bh8*>(KW + (size_t)(b * 128 + row) * 256 + c * 8);
    *reinterpret_cast<bh8*>((char*)kw_l + row * 512 + ((c ^ (row & 31)) << 4)) = v;
  }
  if (tid < 256){ h_l[tid] = hfin[b * 256 + tid]; c_l[tid] = cfin[b * 256 + tid]; }
  __syncthreads();

  const unsigned short* wr = Whh_bf + (size_t)tid * 256;
  const unsigned short* vt = VWWT + (size_t)tid * 2048 + b * 128;

  for (int t = 0; t < 63; ++t){
    // ---- scores: thread s<128, KW row from swizzled LDS ----
    if (tid < 128){
      float a = 0.f;
#pragma unroll
      for (int p = 0; p < 32; ++p){
        U8 ku;
        ku.v = *reinterpret_cast<const bh8*>((char*)kw_l + tid * 512 + (p << 4));
        const float* hp = h_l + ((p ^ (tid & 31)) << 3);   // logical chunk index
#pragma unroll
        for (int q = 0; q < 8; ++q) a += hp[q] * bf2f(ku.u[q]);
      }
      sc_l[tid] = (a + sb[b * 128 + tid]) * 0.0625f;
    }
    __syncthreads();
    if (tid < 64){
      float m = fmaxf(sc_l[tid], sc_l[tid + 64]);
      for (int o = 32; o; o >>= 1) m = fmaxf(m, __shfl_xor(m, o));
      if (tid == 0) red0 = m;
    }
    __syncthreads();
    if (tid < 128) sc_l[tid] = __expf(sc_l[tid] - red0);
    __syncthreads();
    if (tid < 64){
      float s = sc_l[tid] + sc_l[tid + 64];
      for (int o = 32; o; o >>= 1) s += __shfl_xor(s, o);
      if (tid == 0) red1 = s;
    }
    __syncthreads();
    if (tid < 128) at_l[tid] = sc_l[tid] / red1;
    __syncthreads();
    // ---- gates: Xd + h@Whh + attn.VWWT (thread = gate row) ----
    {
      float acc = Xd[(size_t)(b * 63 + t) * 1024 + tid];
#pragma unroll
      for (int k16 = 0; k16 < 16; ++k16){
        float4 h0 = *(const float4*)(h_l + k16 * 16);
        float4 h1 = *(const float4*)(h_l + k16 * 16 + 4);
        float4 h2 = *(const float4*)(h_l + k16 * 16 + 8);
        float4 h3 = *(const float4*)(h_l + k16 * 16 + 12);
        U8 w0, w1;
        w0.v = *reinterpret_cast<const bh8*>(wr + k16 * 16);
        w1.v = *reinterpret_cast<const bh8*>(wr + k16 * 16 + 8);
        acc += h0.x*bf2f(w0.u[0]) + h0.y*bf2f(w0.u[1]) + h0.z*bf2f(w0.u[2]) + h0.w*bf2f(w0.u[3]);
        acc += h1.x*bf2f(w0.u[4]) + h1.y*bf2f(w0.u[5]) + h1.z*bf2f(w0.u[6]) + h1.w*bf2f(w0.u[7]);
        acc += h2.x*bf2f(w1.u[0]) + h2.y*bf2f(w1.u[1]) + h2.z*bf2f(w1.u[2]) + h2.w*bf2f(w1.u[3]);
        acc += h3.x*bf2f(w1.u[4]) + h3.y*bf2f(w1.u[5]) + h3.z*bf2f(w1.u[6]) + h3.w*bf2f(w1.u[7]);
      }
#pragma unroll
      for (int s8 = 0; s8 < 16; ++s8){
        U8 vv; vv.v = *reinterpret_cast<const bh8*>(vt + s8 * 8);
        const float* ap = at_l + s8 * 8;
#pragma unroll
        for (int q = 0; q < 8; ++q) acc += ap[q] * bf2f(vv.u[q]);
      }
      g_l[tid] = acc;
    }
    __syncthreads();
    if (tid < 256){
      float gi = g_l[tid], gf = g_l[256 + tid], gg = g_l[512 + tid], go = g_l[768 + tid];
      float c = sigm(gf) * c_l[tid] + sigm(gi) * tanhf(gg);
      float h = sigm(go) * tanhf(c);
      c_l[tid] = c; h_l[tid] = h;
      Hs[(size_t)(b * 63 + t) * 256 + tid] = f2bf(h);
    }
    __syncthreads();
  }
}

// ---------------- host ----------------
extern "C" void kernel_launch(void* const* d_in, const int* in_sizes, int n_in,
                              void* d_out, int out_size, void* d_ws, size_t ws_size,
                              hipStream_t stream){
  const int expect[20] = {2048, 1024, 8192000, 262144, 262144, 1024, 8192000,
                          65536, 256, 65536, 256, 65536, 256, 65536, 256,
                          524288, 262144, 1024, 8192000, 32000};
  if (n_in != 20 || out_size != 32256000) return;
  for (int i = 0; i < 20; ++i) if (in_sizes[i] != expect[i]) return;

  const int*   input_seq  = (const int*)  d_in[0];
  const int*   target_seq = (const int*)  d_in[1];
  const float* enc_emb    = (const float*)d_in[2];
  const float* enc_Wih    = (const float*)d_in[3];
  const float* enc_Whh    = (const float*)d_in[4];
  const float* enc_b      = (const float*)d_in[5];
  const float* dec_emb    = (const float*)d_in[6];
  const float* Wq         = (const float*)d_in[7];
  const float* bq         = (const float*)d_in[8];
  const float* Wk         = (const float*)d_in[9];
  const float* bk         = (const float*)d_in[10];
  const float* Wv         = (const float*)d_in[11];
  const float* bv         = (const float*)d_in[12];
  const float* Wo         = (const float*)d_in[13];
  const float* bo         = (const float*)d_in[14];
  const float* dec_Wih    = (const float*)d_in[15];
  const float* dec_Whh    = (const float*)d_in[16];
  const float* dec_b      = (const float*)d_in[17];
  const float* Wout       = (const float*)d_in[18];
  const float* bout       = (const float*)d_in[19];

  char* p = (char*)d_ws;
  auto alloc = [&](size_t sz)->char*{ char* r = p; p += (sz + 255) & ~(size_t)255; return r; };

  // ---- zero zone (memset every call): Hs tail rows stay 0 ----
  unsigned short* Hs     = (unsigned short*)alloc((size_t)1024 * 256 * 2);
  size_t zsz = (size_t)(p - (char*)d_ws);
  // ---- working buffers (fully written before read) ----
  unsigned short* src_bf  = (unsigned short*)alloc((size_t)2048 * 256 * 2);
  unsigned short* tok_bf  = (unsigned short*)alloc((size_t)1024 * 256 * 2);
  unsigned short* wih_bf  = (unsigned short*)alloc((size_t)1024 * 256 * 2);
  unsigned short* wxd_bf  = (unsigned short*)alloc((size_t)1024 * 256 * 2);
  unsigned short* wout_bf = (unsigned short*)alloc((size_t)32000 * 256 * 2);
  unsigned short* whhE_bf = (unsigned short*)alloc((size_t)1024 * 256 * 2);
  unsigned short* whhD_bf = (unsigned short*)alloc((size_t)1024 * 256 * 2);
  float*          Gf      = (float*)         alloc((size_t)1024 * 256 * 4);
  unsigned short* A3bf    = (unsigned short*)alloc((size_t)256 * 256 * 2);
  unsigned short* A2bf    = (unsigned short*)alloc((size_t)1024 * 256 * 2);
  float*          c3f     = (float*)         alloc(256 * 4);
  float*          c4f     = (float*)         alloc(256 * 4);
  float*          c5f     = (float*)         alloc(256);
  float*          xdb     = (float*)         alloc(1024 * 4);
  float*          Xg      = (float*)         alloc((size_t)2048 * 1024 * 4);
  float*          Xd      = (float*)         alloc((size_t)1024 * 1024 * 4);
  unsigned short* enc_bf  = (unsigned short*)alloc((size_t)2048 * 256 * 2);
  unsigned short* KWb     = (unsigned short*)alloc((size_t)2048 * 256 * 2);
  unsigned short* VWWT    = (unsigned short*)alloc((size_t)1024 * 2048 * 2);
  float*          sbf     = (float*)         alloc(2048 * 4);
  float*          hfin    = (float*)         alloc(16 * 256 * 4);
  float*          cfin    = (float*)         alloc(16 * 256 * 4);
  if ((size_t)(p - (char*)d_ws) > ws_size) return;

  hipMemsetAsync(d_ws, 0, zsz, stream);

  // prep
  k_gather_src<<<2048, 64, 0, stream>>>(input_seq, enc_emb, src_bf);
  k_gather_tok<<<1024, 64, 0, stream>>>(target_seq, dec_emb, tok_bf);
  k_conv<<<1024, 256, 0, stream>>>(enc_Wih, wih_bf, 1024, 256);
  k_conv<<<1024, 256, 0, stream>>>(dec_Wih, wxd_bf, 1024, 512);
  k_conv<<<1024, 256, 0, stream>>>(Wout,    wout_bf, 32000, 256);
  k_conv<<<1024, 256, 0, stream>>>(enc_Whh, whhE_bf, 1024, 256);
  k_conv<<<1024, 256, 0, stream>>>(dec_Whh, whhD_bf, 1024, 256);

  // folds
  k_fold<<<(1024*256+255)/256, 256, 0, stream>>>(dec_Wih,256,512,1, Wo,0,1,256, nullptr, Gf,nullptr, 1024,256);
  k_fold<<<(256*256+255)/256,  256, 0, stream>>>(Wq,0,1,256,        Wk,0,1,256, nullptr, nullptr,A3bf, 256,256);
  k_fold<<<1,                  256, 0, stream>>>(bk,0,0,1,          Wq,0,1,256, nullptr, c3f,nullptr, 1,256);
  k_fold<<<1,                  256, 0, stream>>>(bq,0,0,1,          Wk,0,1,256, nullptr, c4f,nullptr, 1,256);
  k_fold<<<1,                  256, 0, stream>>>(bq,0,0,1,          bk,0,0,1,   nullptr, c5f,nullptr, 1,1);
  k_fold<<<(1024+255)/256,     256, 0, stream>>>(dec_Wih,256,512,1, bo,0,0,1,   dec_b,   xdb,nullptr, 1024,1);
  k_fold<<<(1024*256+255)/256, 256, 0, stream>>>(Gf,0,256,1,        Wv,0,1,256, nullptr, nullptr,A2bf, 1024,256);
  // fold c2 = Gf.bv INTO xdb (valid since sum(attn)=1); in-place add, ordered after xdb fold
  k_fold<<<(1024+255)/256,     256, 0, stream>>>(Gf,0,256,1,        bv,0,0,1,   xdb,     xdb,nullptr, 1024,1);

  // big parallel GEMMs
  k_gemm<<<dim3(8, 16),  256, 0, stream>>>(src_bf, wih_bf, enc_b, Xg, nullptr, 2048, 1024);
  k_gemm<<<dim3(8, 8),   256, 0, stream>>>(tok_bf, wxd_bf, xdb,   Xd, nullptr, 1024, 1024);

  // encoder: block = batch, no global sync
  k_enc_b<<<16, 1024, 0, stream>>>(whhE_bf, Xg, enc_bf, hfin, cfin);

  // attention precomputes
  k_gemm<<<dim3(2, 16),  256, 0, stream>>>(enc_bf, A3bf, c3f, nullptr, KWb,  2048, 256);
  // VWWT[r][(b,s)]: swap operand order -> transposed layout directly (bias folded into xdb)
  k_gemm<<<dim3(16, 8),  256, 0, stream>>>(A2bf, enc_bf, nullptr, nullptr, VWWT, 1024, 2048);
  k_sb<<<8, 256, 0, stream>>>(enc_bf, c4f, c5f, sbf);

  // decoder: block = batch, no global sync
  k_dec_b<<<16, 1024, 0, stream>>>(whhD_bf, Xd, KWb, VWWT, sbf, hfin, cfin, Hs);

  // logits: (1008 x 32000) = Hs @ Wout^T + bout -> FP32 d_out
  k_gemm<<<dim3(250, 8), 256, 0, stream>>>(Hs, wout_bf, bout, (float*)d_out, nullptr, 1008, 32000);
}

// Round 8
// 2305.315 us; speedup vs baseline: 1.6737x; 1.6737x over previous
//
#include <hip/hip_runtime.h>

// ---------------- types / helpers ----------------
typedef short bh8 __attribute__((ext_vector_type(8)));     // 8 x bf16 raw
typedef float f32x4 __attribute__((ext_vector_type(4)));

#define DEVI __device__ __forceinline__

union U8 { bh8 v; unsigned short u[8]; };

DEVI float bf2f(unsigned short u){
  unsigned int x = ((unsigned int)u) << 16;
  return __builtin_bit_cast(float, x);
}
DEVI unsigned short f2bf(float f){
  unsigned int u = __builtin_bit_cast(unsigned int, f);
  u += 0x7fffu + ((u >> 16) & 1u);
  return (unsigned short)(u >> 16);
}
DEVI float sigm(float x){ return 1.0f/(1.0f + __expf(-x)); }

DEVI f32x4 MFMA(bh8 a, bh8 b, f32x4 c){
  return __builtin_amdgcn_mfma_f32_16x16x32_bf16(a, b, c, 0, 0, 0);
}

// group barrier: nb arrivals on one counter; counters zeroed per launch
DEVI void gbar(int* c, int nb){
  __syncthreads();
  if (threadIdx.x == 0){
    __threadfence();
    __hip_atomic_fetch_add(c, 1, __ATOMIC_RELEASE, __HIP_MEMORY_SCOPE_AGENT);
    int it = 0;
    while (__hip_atomic_load(c, __ATOMIC_ACQUIRE, __HIP_MEMORY_SCOPE_AGENT) < nb
           && ++it < (1 << 25)) { }
    __threadfence();
  }
  __syncthreads();
}

// ---------------- prep kernels (unchanged, validated) ----------------
__global__ void k_gather_src(const int* seq, const float* emb, unsigned short* dst){
  int m = blockIdx.x;
  int idx = seq[m];
  const float* s = emb + (size_t)idx * 256;
  unsigned short* d = dst + (size_t)m * 256;
  for (int e = threadIdx.x; e < 256; e += 64) d[e] = f2bf(s[e]);
}

__global__ void k_gather_tok(const int* tseq, const float* emb, unsigned short* dst){
  int m = blockIdx.x;
  unsigned short* d = dst + (size_t)m * 256;
  if (m < 1008){
    int b = m / 63, t = m - b * 63;
    int idx = tseq[b * 64 + t];
    const float* s = emb + (size_t)idx * 256;
    for (int e = threadIdx.x; e < 256; e += 64) d[e] = f2bf(s[e]);
  } else {
    for (int e = threadIdx.x; e < 256; e += 64) d[e] = 0;
  }
}

__global__ void k_conv(const float* src, unsigned short* dst, int rows, int rstride){
  size_t n = (size_t)rows * 128;
  for (size_t i = (size_t)blockIdx.x * 256 + threadIdx.x; i < n; i += (size_t)gridDim.x * 256){
    size_t r = i >> 7; int c = ((int)(i & 127)) * 2;
    const float* s = src + r * (size_t)rstride + c;
    unsigned int hp = (unsigned int)f2bf(s[0]) | ((unsigned int)f2bf(s[1]) << 16);
    *(unsigned int*)(dst + r * 256 + c) = hp;
  }
}

__global__ void k_fold(const float* A, int offA, int sAm, int sAk,
                       const float* Bm, int offB, int sBn, int sBk,
                       const float* addM, float* Cf, unsigned short* Cb,
                       int M, int N){
  int i = blockIdx.x * 256 + threadIdx.x;
  if (i >= M * N) return;
  int m = i / N, n = i - m * N;
  const float* a = A + offA + (size_t)m * sAm;
  const float* b = Bm + offB + (size_t)n * sBn;
  float acc = 0.f;
  for (int k = 0; k < 256; ++k) acc += a[(size_t)k * sAk] * b[(size_t)k * sBk];
  if (addM) acc += addM[m];
  if (Cf) Cf[i] = acc;
  if (Cb) Cb[i] = f2bf(acc);
}

__global__ void k_sb(const unsigned short* enc, const float* c4, const float* c5, float* sb){
  int m = blockIdx.x * 256 + threadIdx.x;
  if (m >= 2048) return;
  const unsigned short* e = enc + (size_t)m * 256;
  float a = 0.f;
  for (int k = 0; k < 256; ++k) a += bf2f(e[k]) * c4[k];
  sb[m] = a + c5[0];
}

// ---------------- bf16 MFMA GEMM, K=256 fixed (validated) ----------------
__global__ __launch_bounds__(256) void k_gemm(const unsigned short* __restrict__ A,
      const unsigned short* __restrict__ Bw, const float* __restrict__ bias,
      float* __restrict__ Cf, unsigned short* __restrict__ Cb, int Mlog, int N){
  __shared__ __align__(16) unsigned short lA[128 * 32];
  __shared__ __align__(16) unsigned short lB[128 * 32];
  int tid = threadIdx.x;
  int lane = tid & 63, wave = tid >> 6;
  int wm = wave >> 1, wn = wave & 1;
  int kg = lane >> 4, l15 = lane & 15;
  size_t tm = blockIdx.y, tn = blockIdx.x;
  f32x4 acc[4][4];
#pragma unroll
  for (int i = 0; i < 4; ++i)
#pragma unroll
    for (int j = 0; j < 4; ++j) acc[i][j] = (f32x4){0.f, 0.f, 0.f, 0.f};

  for (int ks = 0; ks < 8; ++ks){
    __syncthreads();
#pragma unroll
    for (int i = 0; i < 2; ++i){
      int slot = i * 256 + tid;
      int r = slot >> 2, sg = slot & 3;
      bh8 va = *reinterpret_cast<const bh8*>(A + (tm * 128 + r) * 256 + ks * 32 + sg * 8);
      *reinterpret_cast<bh8*>((char*)lA + r * 64 + ((sg ^ (r & 3)) << 4)) = va;
      bh8 vb = *reinterpret_cast<const bh8*>(Bw + (tn * 128 + r) * 256 + ks * 32 + sg * 8);
      *reinterpret_cast<bh8*>((char*)lB + r * 64 + ((sg ^ (r & 3)) << 4)) = vb;
    }
    __syncthreads();
    bh8 af[4], bfr[4];
#pragma unroll
    for (int mi = 0; mi < 4; ++mi){
      int r = wm * 64 + mi * 16 + l15;
      af[mi] = *reinterpret_cast<const bh8*>((char*)lA + r * 64 + ((kg ^ (r & 3)) << 4));
    }
#pragma unroll
    for (int ni = 0; ni < 4; ++ni){
      int r = wn * 64 + ni * 16 + l15;
      bfr[ni] = *reinterpret_cast<const bh8*>((char*)lB + r * 64 + ((kg ^ (r & 3)) << 4));
    }
#pragma unroll
    for (int mi = 0; mi < 4; ++mi)
#pragma unroll
      for (int ni = 0; ni < 4; ++ni)
        acc[mi][ni] = MFMA(af[mi], bfr[ni], acc[mi][ni]);
  }
#pragma unroll
  for (int ni = 0; ni < 4; ++ni){
    int col = (int)tn * 128 + wn * 64 + ni * 16 + l15;
    float bv = bias ? bias[col] : 0.f;
#pragma unroll
    for (int mi = 0; mi < 4; ++mi){
#pragma unroll
      for (int rg = 0; rg < 4; ++rg){
        int row = (int)tm * 128 + wm * 64 + mi * 16 + kg * 4 + rg;
        if (row < Mlog){
          float v = acc[mi][ni][rg] + bv;
          if (Cb) Cb[(size_t)row * N + col] = f2bf(v);
          else    Cf[(size_t)row * N + col] = v;
        }
      }
    }
  }
}

// ---------------- grouped encoder: 128 blocks = 16 batches x 8 sub-blocks ----------------
// group = blockIdx&15 (same-XCD heuristic). Block owns 128 gate rows: {g*256+sub*32+jj}.
// Whh slice LDS-resident (64KB, XOR-swizzled). h exchanged via global fp32 (1 load/thread).
__global__ __launch_bounds__(256) void k_enc_g(const unsigned short* __restrict__ Whh_bf,
      const float* __restrict__ Xg, unsigned short* __restrict__ enc_bf,
      float* hbufE, float* hbufD, float* cfin, int* bar){
  __shared__ __align__(16) unsigned short Ws[128 * 256];  // 64 KB
  __shared__ __align__(16) float h_l[256];
  __shared__ float part[256];
  int tid = threadIdx.x, blk = blockIdx.x;
  int b = blk & 15, sub = blk >> 4, j0 = sub * 32;
  int lr = tid >> 1, kh = tid & 1;

  // stage Whh slice, 16B chunks, chunk^(lr&31) swizzle
  for (int i = 0; i < 16; ++i){
    int id = i * 256 + tid;
    int slr = id >> 5, c = id & 31;
    int R = (slr >> 5) * 256 + j0 + (slr & 31);
    bh8 v = *reinterpret_cast<const bh8*>(Whh_bf + (size_t)R * 256 + c * 8);
    *reinterpret_cast<bh8*>((char*)Ws + slr * 512 + ((c ^ (slr & 31)) << 4)) = v;
  }
  float creg = 0.f;
  int Rr = (lr >> 5) * 256 + j0 + (lr & 31);
  __syncthreads();

  for (int t = 0; t < 128; ++t){
    // load h_t (fp32, 1 elem/thread)
    {
      unsigned int v = __hip_atomic_load((const unsigned int*)hbufE + (t & 1) * 4096 + b * 256 + tid,
                                         __ATOMIC_RELAXED, __HIP_MEMORY_SCOPE_AGENT);
      h_l[tid] = __builtin_bit_cast(float, v);
    }
    __syncthreads();
    // partial: thread (lr, kh) does half-row dot
    {
      float acc = (kh == 0) ? Xg[(size_t)(b * 128 + t) * 1024 + Rr] : 0.f;
#pragma unroll
      for (int ci = 0; ci < 16; ++ci){
        int chunk = kh * 16 + ci;
        U8 w; w.v = *reinterpret_cast<const bh8*>((char*)Ws + lr * 512 + ((chunk ^ (lr & 31)) << 4));
        float4 ha = *(const float4*)(h_l + chunk * 8);
        float4 hb = *(const float4*)(h_l + chunk * 8 + 4);
        acc += ha.x*bf2f(w.u[0]) + ha.y*bf2f(w.u[1]) + ha.z*bf2f(w.u[2]) + ha.w*bf2f(w.u[3]);
        acc += hb.x*bf2f(w.u[4]) + hb.y*bf2f(w.u[5]) + hb.z*bf2f(w.u[6]) + hb.w*bf2f(w.u[7]);
      }
      part[tid] = acc;
    }
    __syncthreads();
    if (tid < 32){
      float gi = part[tid*2]          + part[tid*2 + 1];
      float gf = part[(32+tid)*2]     + part[(32+tid)*2 + 1];
      float gg = part[(64+tid)*2]     + part[(64+tid)*2 + 1];
      float go = part[(96+tid)*2]     + part[(96+tid)*2 + 1];
      float c = sigm(gf) * creg + sigm(gi) * tanhf(gg);
      float h = sigm(go) * tanhf(c);
      creg = c;
      int j = j0 + tid;
      if (t < 127){
        __hip_atomic_store((unsigned int*)hbufE + ((t + 1) & 1) * 4096 + b * 256 + j,
                           __builtin_bit_cast(unsigned int, h), __ATOMIC_RELAXED, __HIP_MEMORY_SCOPE_AGENT);
      } else {
        __hip_atomic_store((unsigned int*)hbufD + b * 256 + j,
                           __builtin_bit_cast(unsigned int, h), __ATOMIC_RELAXED, __HIP_MEMORY_SCOPE_AGENT);
        cfin[b * 256 + j] = c;
      }
      enc_bf[(size_t)(b * 128 + t) * 256 + j] = f2bf(h);
    }
    gbar(bar + b * 128 + t, 8);
  }
}

// ---------------- grouped decoder: 128 blocks = 16 batches x 8 sub-blocks ----------------
// Per block LDS: Whh slice 64KB + KW slice 8KB + VWWT slice 32KB. 2 group barriers/step.
__global__ __launch_bounds__(256) void k_dec_g(const unsigned short* __restrict__ Whh_bf,
      const float* __restrict__ Xd, const unsigned short* __restrict__ KW,
      const unsigned short* __restrict__ VWWT, const float* __restrict__ sb,
      float* hbufD, const float* __restrict__ cfin, float* scoreG,
      unsigned short* __restrict__ Hs, int* bar){
  __shared__ __align__(16) unsigned short Ws[128 * 256];   // 64 KB
  __shared__ __align__(16) unsigned short KW_l[16 * 256];  // 8 KB
  __shared__ __align__(16) unsigned short VW_l[128 * 128]; // 32 KB
  __shared__ __align__(16) float h_l[256];
  __shared__ float part[256];
  __shared__ float sc_l[128];
  __shared__ float at_l[128];
  __shared__ float red0, red1;
  int tid = threadIdx.x, blk = blockIdx.x;
  int b = blk & 15, sub = blk >> 4, j0 = sub * 32;
  int lr = tid >> 1, kh = tid & 1;

  // stage Whh slice (swizzled)
  for (int i = 0; i < 16; ++i){
    int id = i * 256 + tid;
    int slr = id >> 5, c = id & 31;
    int R = (slr >> 5) * 256 + j0 + (slr & 31);
    bh8 v = *reinterpret_cast<const bh8*>(Whh_bf + (size_t)R * 256 + c * 8);
    *reinterpret_cast<bh8*>((char*)Ws + slr * 512 + ((c ^ (slr & 31)) << 4)) = v;
  }
  // stage KW slice (16 source rows, linear)
  for (int i = 0; i < 2; ++i){
    int id = i * 256 + tid;
    int slr = id >> 5, c = id & 31;
    bh8 v = *reinterpret_cast<const bh8*>(KW + (size_t)(b * 128 + sub * 16 + slr) * 256 + c * 8);
    *reinterpret_cast<bh8*>((char*)KW_l + slr * 512 + (c << 4)) = v;
  }
  // stage VWWT slice (swizzled by lr&15)
  for (int i = 0; i < 8; ++i){
    int id = i * 256 + tid;
    int slr = id >> 4, c = id & 15;
    int R = (slr >> 5) * 256 + j0 + (slr & 31);
    bh8 v = *reinterpret_cast<const bh8*>(VWWT + (size_t)R * 2048 + b * 128 + c * 8);
    *reinterpret_cast<bh8*>((char*)VW_l + slr * 256 + ((c ^ (slr & 15)) << 4)) = v;
  }
  float creg = (tid < 32) ? cfin[b * 256 + j0 + tid] : 0.f;
  int Rr = (lr >> 5) * 256 + j0 + (lr & 31);
  __syncthreads();

  int* barD = bar;
  for (int t = 0; t < 63; ++t){
    // load h_t
    {
      unsigned int v = __hip_atomic_load((const unsigned int*)hbufD + (t & 1) * 4096 + b * 256 + tid,
                                         __ATOMIC_RELAXED, __HIP_MEMORY_SCOPE_AGENT);
      h_l[tid] = __builtin_bit_cast(float, v);
    }
    __syncthreads();
    // scores partial: thread (ss=tid>>4, kq=tid&15) over k in [kq*16, kq*16+16)
    {
      int ss = tid >> 4, kq = tid & 15;
      float a = 0.f;
#pragma unroll
      for (int i = 0; i < 2; ++i){
        U8 ku; ku.v = *reinterpret_cast<const bh8*>((char*)KW_l + ss * 512 + ((kq * 2 + i) << 4));
        const float* hp = h_l + kq * 16 + i * 8;
#pragma unroll
        for (int q = 0; q < 8; ++q) a += hp[q] * bf2f(ku.u[q]);
      }
      part[tid] = a;
    }
    __syncthreads();
    if (tid < 16){
      float s = 0.f;
#pragma unroll
      for (int q = 0; q < 16; ++q) s += part[tid * 16 + q];
      int sidx = sub * 16 + tid;
      s = (s + sb[b * 128 + sidx]) * 0.0625f;
      __hip_atomic_store((unsigned int*)scoreG + b * 128 + sidx,
                         __builtin_bit_cast(unsigned int, s), __ATOMIC_RELAXED, __HIP_MEMORY_SCOPE_AGENT);
    }
    // Whh partial (overlaps other blocks' score phase); keep in register
    float wacc = (kh == 0) ? Xd[(size_t)(b * 63 + t) * 1024 + Rr] : 0.f;
#pragma unroll
    for (int ci = 0; ci < 16; ++ci){
      int chunk = kh * 16 + ci;
      U8 w; w.v = *reinterpret_cast<const bh8*>((char*)Ws + lr * 512 + ((chunk ^ (lr & 31)) << 4));
      float4 ha = *(const float4*)(h_l + chunk * 8);
      float4 hb = *(const float4*)(h_l + chunk * 8 + 4);
      wacc += ha.x*bf2f(w.u[0]) + ha.y*bf2f(w.u[1]) + ha.z*bf2f(w.u[2]) + ha.w*bf2f(w.u[3]);
      wacc += hb.x*bf2f(w.u[4]) + hb.y*bf2f(w.u[5]) + hb.z*bf2f(w.u[6]) + hb.w*bf2f(w.u[7]);
    }
    __syncthreads();           // part[] score reads done
    part[tid] = wacc;
    gbar(barD + (b * 63 + t) * 2, 8);
    // softmax (redundant per block)
    if (tid < 128){
      unsigned int v = __hip_atomic_load((const unsigned int*)scoreG + b * 128 + tid,
                                         __ATOMIC_RELAXED, __HIP_MEMORY_SCOPE_AGENT);
      sc_l[tid] = __builtin_bit_cast(float, v);
    }
    __syncthreads();
    if (tid < 64){
      float m = fmaxf(sc_l[tid], sc_l[tid + 64]);
      for (int o = 32; o; o >>= 1) m = fmaxf(m, __shfl_xor(m, o));
      if (tid == 0) red0 = m;
    }
    __syncthreads();
    if (tid < 128) sc_l[tid] = __expf(sc_l[tid] - red0);
    __syncthreads();
    if (tid < 64){
      float s = sc_l[tid] + sc_l[tid + 64];
      for (int o = 32; o; o >>= 1) s += __shfl_xor(s, o);
      if (tid == 0) red1 = s;
    }
    __syncthreads();
    if (tid < 128) at_l[tid] = sc_l[tid] / red1;
    __syncthreads();
    // VWW partial: thread (lr, kh) over s in [kh*64, kh*64+64)
    {
      float acc = 0.f;
#pragma unroll
      for (int sc8 = 0; sc8 < 8; ++sc8){
        int chunk = kh * 8 + sc8;
        U8 vv; vv.v = *reinterpret_cast<const bh8*>((char*)VW_l + lr * 256 + ((chunk ^ (lr & 15)) << 4));
        float4 aa = *(const float4*)(at_l + chunk * 8);
        float4 ab = *(const float4*)(at_l + chunk * 8 + 4);
        acc += aa.x*bf2f(vv.u[0]) + aa.y*bf2f(vv.u[1]) + aa.z*bf2f(vv.u[2]) + aa.w*bf2f(vv.u[3]);
        acc += ab.x*bf2f(vv.u[4]) + ab.y*bf2f(vv.u[5]) + ab.z*bf2f(vv.u[6]) + ab.w*bf2f(vv.u[7]);
      }
      part[tid] += acc;
    }
    __syncthreads();
    if (tid < 32){
      float gi = part[tid*2]          + part[tid*2 + 1];
      float gf = part[(32+tid)*2]     + part[(32+tid)*2 + 1];
      float gg = part[(64+tid)*2]     + part[(64+tid)*2 + 1];
      float go = part[(96+tid)*2]     + part[(96+tid)*2 + 1];
      float c = sigm(gf) * creg + sigm(gi) * tanhf(gg);
      float h = sigm(go) * tanhf(c);
      creg = c;
      int j = j0 + tid;
      __hip_atomic_store((unsigned int*)hbufD + ((t + 1) & 1) * 4096 + b * 256 + j,
                         __builtin_bit_cast(unsigned int, h), __ATOMIC_RELAXED, __HIP_MEMORY_SCOPE_AGENT);
      Hs[(size_t)(b * 63 + t) * 256 + j] = f2bf(h);
    }
    gbar(barD + (b * 63 + t) * 2 + 1, 8);
  }
}

// ---------------- host ----------------
extern "C" void kernel_launch(void* const* d_in, const int* in_sizes, int n_in,
                              void* d_out, int out_size, void* d_ws, size_t ws_size,
                              hipStream_t stream){
  const int expect[20] = {2048, 1024, 8192000, 262144, 262144, 1024, 8192000,
                          65536, 256, 65536, 256, 65536, 256, 65536, 256,
                          524288, 262144, 1024, 8192000, 32000};
  if (n_in != 20 || out_size != 32256000) return;
  for (int i = 0; i < 20; ++i) if (in_sizes[i] != expect[i]) return;

  const int*   input_seq  = (const int*)  d_in[0];
  const int*   target_seq = (const int*)  d_in[1];
  const float* enc_emb    = (const float*)d_in[2];
  const float* enc_Wih    = (const float*)d_in[3];
  const float* enc_Whh    = (const float*)d_in[4];
  const float* enc_b      = (const float*)d_in[5];
  const float* dec_emb    = (const float*)d_in[6];
  const float* Wq         = (const float*)d_in[7];
  const float* bq         = (const float*)d_in[8];
  const float* Wk         = (const float*)d_in[9];
  const float* bk         = (const float*)d_in[10];
  const float* Wv         = (const float*)d_in[11];
  const float* bv         = (const float*)d_in[12];
  const float* Wo         = (const float*)d_in[13];
  const float* bo         = (const float*)d_in[14];
  const float* dec_Wih    = (const float*)d_in[15];
  const float* dec_Whh    = (const float*)d_in[16];
  const float* dec_b      = (const float*)d_in[17];
  const float* Wout       = (const float*)d_in[18];
  const float* bout       = (const float*)d_in[19];

  char* p = (char*)d_ws;
  auto alloc = [&](size_t sz)->char*{ char* r = p; p += (sz + 255) & ~(size_t)255; return r; };

  // ---- zero zone (memset every call) ----
  unsigned short* Hs     = (unsigned short*)alloc((size_t)1024 * 256 * 2);
  int*            bar    = (int*)           alloc((2048 + 2016) * 4);   // enc 16*128 + dec 16*63*2
  float*          hbufE  = (float*)         alloc(2 * 4096 * 4);
  size_t zsz = (size_t)(p - (char*)d_ws);
  // ---- working buffers (fully written before read) ----
  float*          hbufD  = (float*)          alloc(2 * 4096 * 4);
  float*          cfin   = (float*)          alloc(16 * 256 * 4);
  float*          scoreG = (float*)          alloc(16 * 128 * 4);
  unsigned short* src_bf  = (unsigned short*)alloc((size_t)2048 * 256 * 2);
  unsigned short* tok_bf  = (unsigned short*)alloc((size_t)1024 * 256 * 2);
  unsigned short* wih_bf  = (unsigned short*)alloc((size_t)1024 * 256 * 2);
  unsigned short* wxd_bf  = (unsigned short*)alloc((size_t)1024 * 256 * 2);
  unsigned short* wout_bf = (unsigned short*)alloc((size_t)32000 * 256 * 2);
  unsigned short* whhE_bf = (unsigned short*)alloc((size_t)1024 * 256 * 2);
  unsigned short* whhD_bf = (unsigned short*)alloc((size_t)1024 * 256 * 2);
  float*          Gf      = (float*)         alloc((size_t)1024 * 256 * 4);
  unsigned short* A3bf    = (unsigned short*)alloc((size_t)256 * 256 * 2);
  unsigned short* A2bf    = (unsigned short*)alloc((size_t)1024 * 256 * 2);
  float*          c3f     = (float*)         alloc(256 * 4);
  float*          c4f     = (float*)         alloc(256 * 4);
  float*          c5f     = (float*)         alloc(256);
  float*          xdb     = (float*)         alloc(1024 * 4);
  float*          Xg      = (float*)         alloc((size_t)2048 * 1024 * 4);
  float*          Xd      = (float*)         alloc((size_t)1024 * 1024 * 4);
  unsigned short* enc_bf  = (unsigned short*)alloc((size_t)2048 * 256 * 2);
  unsigned short* KWb     = (unsigned short*)alloc((size_t)2048 * 256 * 2);
  unsigned short* VWWT    = (unsigned short*)alloc((size_t)1024 * 2048 * 2);
  float*          sbf     = (float*)         alloc(2048 * 4);
  if ((size_t)(p - (char*)d_ws) > ws_size) return;

  hipMemsetAsync(d_ws, 0, zsz, stream);

  // prep
  k_gather_src<<<2048, 64, 0, stream>>>(input_seq, enc_emb, src_bf);
  k_gather_tok<<<1024, 64, 0, stream>>>(target_seq, dec_emb, tok_bf);
  k_conv<<<1024, 256, 0, stream>>>(enc_Wih, wih_bf, 1024, 256);
  k_conv<<<1024, 256, 0, stream>>>(dec_Wih, wxd_bf, 1024, 512);
  k_conv<<<1024, 256, 0, stream>>>(Wout,    wout_bf, 32000, 256);
  k_conv<<<1024, 256, 0, stream>>>(enc_Whh, whhE_bf, 1024, 256);
  k_conv<<<1024, 256, 0, stream>>>(dec_Whh, whhD_bf, 1024, 256);

  // folds
  k_fold<<<(1024*256+255)/256, 256, 0, stream>>>(dec_Wih,256,512,1, Wo,0,1,256, nullptr, Gf,nullptr, 1024,256);
  k_fold<<<(256*256+255)/256,  256, 0, stream>>>(Wq,0,1,256,        Wk,0,1,256, nullptr, nullptr,A3bf, 256,256);
  k_fold<<<1,                  256, 0, stream>>>(bk,0,0,1,          Wq,0,1,256, nullptr, c3f,nullptr, 1,256);
  k_fold<<<1,                  256, 0, stream>>>(bq,0,0,1,          Wk,0,1,256, nullptr, c4f,nullptr, 1,256);
  k_fold<<<1,                  256, 0, stream>>>(bq,0,0,1,          bk,0,0,1,   nullptr, c5f,nullptr, 1,1);
  k_fold<<<(1024+255)/256,     256, 0, stream>>>(dec_Wih,256,512,1, bo,0,0,1,   dec_b,   xdb,nullptr, 1024,1);
  k_fold<<<(1024*256+255)/256, 256, 0, stream>>>(Gf,0,256,1,        Wv,0,1,256, nullptr, nullptr,A2bf, 1024,256);
  k_fold<<<(1024+255)/256,     256, 0, stream>>>(Gf,0,256,1,        bv,0,0,1,   xdb,     xdb,nullptr, 1024,1);

  // big parallel GEMMs
  k_gemm<<<dim3(8, 16),  256, 0, stream>>>(src_bf, wih_bf, enc_b, Xg, nullptr, 2048, 1024);
  k_gemm<<<dim3(8, 8),   256, 0, stream>>>(tok_bf, wxd_bf, xdb,   Xd, nullptr, 1024, 1024);

  // encoder: 16 groups x 8 blocks, group barrier only
  k_enc_g<<<128, 256, 0, stream>>>(whhE_bf, Xg, enc_bf, hbufE, hbufD, cfin, bar);

  // attention precomputes
  k_gemm<<<dim3(2, 16),  256, 0, stream>>>(enc_bf, A3bf, c3f, nullptr, KWb,  2048, 256);
  k_gemm<<<dim3(16, 8),  256, 0, stream>>>(A2bf, enc_bf, nullptr, nullptr, VWWT, 1024, 2048);
  k_sb<<<8, 256, 0, stream>>>(enc_bf, c4f, c5f, sbf);

  // decoder: 16 groups x 8 blocks, 2 group barriers/step
  k_dec_g<<<128, 256, 0, stream>>>(whhD_bf, Xd, KWb, VWWT, sbf, hbufD, cfin, scoreG, Hs, bar + 2048);

  // logits -> FP32 d_out
  k_gemm<<<dim3(250, 8), 256, 0, stream>>>(Hs, wout_bf, bout, (float*)d_out, nullptr, 1008, 32000);
}

// Round 9
// 861.673 us; speedup vs baseline: 4.4778x; 2.6754x over previous
//
#include <hip/hip_runtime.h>

// ---------------- types / helpers ----------------
typedef short bh8 __attribute__((ext_vector_type(8)));     // 8 x bf16 raw
typedef float f32x4 __attribute__((ext_vector_type(4)));

#define DEVI __device__ __forceinline__

union U8 { bh8 v; unsigned short u[8]; };

DEVI float bf2f(unsigned short u){
  unsigned int x = ((unsigned int)u) << 16;
  return __builtin_bit_cast(float, x);
}
DEVI unsigned short f2bf(float f){
  unsigned int u = __builtin_bit_cast(unsigned int, f);
  u += 0x7fffu + ((u >> 16) & 1u);
  return (unsigned short)(u >> 16);
}
DEVI float sigm(float x){ return 1.0f/(1.0f + __expf(-x)); }

DEVI f32x4 MFMA(bh8 a, bh8 b, f32x4 c){
  return __builtin_amdgcn_mfma_f32_16x16x32_bf16(a, b, c, 0, 0, 0);
}

// data-as-flag poll: location written once per call; sentinel = 0xFFFFFFFF (NaN, unreachable)
DEVI float pollf(const unsigned int* pnt){
  unsigned int v; int it = 0;
  do { v = __hip_atomic_load(pnt, __ATOMIC_RELAXED, __HIP_MEMORY_SCOPE_AGENT); }
  while (v == 0xFFFFFFFFu && ++it < (1 << 24));
  return __builtin_bit_cast(float, v);
}

// ---------------- prep kernels (validated) ----------------
__global__ void k_gather_src(const int* seq, const float* emb, unsigned short* dst){
  int m = blockIdx.x;
  int idx = seq[m];
  const float* s = emb + (size_t)idx * 256;
  unsigned short* d = dst + (size_t)m * 256;
  for (int e = threadIdx.x; e < 256; e += 64) d[e] = f2bf(s[e]);
}

__global__ void k_gather_tok(const int* tseq, const float* emb, unsigned short* dst){
  int m = blockIdx.x;
  unsigned short* d = dst + (size_t)m * 256;
  if (m < 1008){
    int b = m / 63, t = m - b * 63;
    int idx = tseq[b * 64 + t];
    const float* s = emb + (size_t)idx * 256;
    for (int e = threadIdx.x; e < 256; e += 64) d[e] = f2bf(s[e]);
  } else {
    for (int e = threadIdx.x; e < 256; e += 64) d[e] = 0;
  }
}

__global__ void k_conv(const float* src, unsigned short* dst, int rows, int rstride){
  size_t n = (size_t)rows * 128;
  for (size_t i = (size_t)blockIdx.x * 256 + threadIdx.x; i < n; i += (size_t)gridDim.x * 256){
    size_t r = i >> 7; int c = ((int)(i & 127)) * 2;
    const float* s = src + r * (size_t)rstride + c;
    unsigned int hp = (unsigned int)f2bf(s[0]) | ((unsigned int)f2bf(s[1]) << 16);
    *(unsigned int*)(dst + r * 256 + c) = hp;
  }
}

__global__ void k_fold(const float* A, int offA, int sAm, int sAk,
                       const float* Bm, int offB, int sBn, int sBk,
                       const float* addM, float* Cf, unsigned short* Cb,
                       int M, int N){
  int i = blockIdx.x * 256 + threadIdx.x;
  if (i >= M * N) return;
  int m = i / N, n = i - m * N;
  const float* a = A + offA + (size_t)m * sAm;
  const float* b = Bm + offB + (size_t)n * sBn;
  float acc = 0.f;
  for (int k = 0; k < 256; ++k) acc += a[(size_t)k * sAk] * b[(size_t)k * sBk];
  if (addM) acc += addM[m];
  if (Cf) Cf[i] = acc;
  if (Cb) Cb[i] = f2bf(acc);
}

__global__ void k_sb(const unsigned short* enc, const float* c4, const float* c5, float* sb){
  int m = blockIdx.x * 256 + threadIdx.x;
  if (m >= 2048) return;
  const unsigned short* e = enc + (size_t)m * 256;
  float a = 0.f;
  for (int k = 0; k < 256; ++k) a += bf2f(e[k]) * c4[k];
  sb[m] = a + c5[0];
}

// ---------------- bf16 MFMA GEMM, K=256 fixed (validated) ----------------
__global__ __launch_bounds__(256) void k_gemm(const unsigned short* __restrict__ A,
      const unsigned short* __restrict__ Bw, const float* __restrict__ bias,
      float* __restrict__ Cf, unsigned short* __restrict__ Cb, int Mlog, int N){
  __shared__ __align__(16) unsigned short lA[128 * 32];
  __shared__ __align__(16) unsigned short lB[128 * 32];
  int tid = threadIdx.x;
  int lane = tid & 63, wave = tid >> 6;
  int wm = wave >> 1, wn = wave & 1;
  int kg = lane >> 4, l15 = lane & 15;
  size_t tm = blockIdx.y, tn = blockIdx.x;
  f32x4 acc[4][4];
#pragma unroll
  for (int i = 0; i < 4; ++i)
#pragma unroll
    for (int j = 0; j < 4; ++j) acc[i][j] = (f32x4){0.f, 0.f, 0.f, 0.f};

  for (int ks = 0; ks < 8; ++ks){
    __syncthreads();
#pragma unroll
    for (int i = 0; i < 2; ++i){
      int slot = i * 256 + tid;
      int r = slot >> 2, sg = slot & 3;
      bh8 va = *reinterpret_cast<const bh8*>(A + (tm * 128 + r) * 256 + ks * 32 + sg * 8);
      *reinterpret_cast<bh8*>((char*)lA + r * 64 + ((sg ^ (r & 3)) << 4)) = va;
      bh8 vb = *reinterpret_cast<const bh8*>(Bw + (tn * 128 + r) * 256 + ks * 32 + sg * 8);
      *reinterpret_cast<bh8*>((char*)lB + r * 64 + ((sg ^ (r & 3)) << 4)) = vb;
    }
    __syncthreads();
    bh8 af[4], bfr[4];
#pragma unroll
    for (int mi = 0; mi < 4; ++mi){
      int r = wm * 64 + mi * 16 + l15;
      af[mi] = *reinterpret_cast<const bh8*>((char*)lA + r * 64 + ((kg ^ (r & 3)) << 4));
    }
#pragma unroll
    for (int ni = 0; ni < 4; ++ni){
      int r = wn * 64 + ni * 16 + l15;
      bfr[ni] = *reinterpret_cast<const bh8*>((char*)lB + r * 64 + ((kg ^ (r & 3)) << 4));
    }
#pragma unroll
    for (int mi = 0; mi < 4; ++mi)
#pragma unroll
      for (int ni = 0; ni < 4; ++ni)
        acc[mi][ni] = MFMA(af[mi], bfr[ni], acc[mi][ni]);
  }
#pragma unroll
  for (int ni = 0; ni < 4; ++ni){
    int col = (int)tn * 128 + wn * 64 + ni * 16 + l15;
    float bv = bias ? bias[col] : 0.f;
#pragma unroll
    for (int mi = 0; mi < 4; ++mi){
#pragma unroll
      for (int rg = 0; rg < 4; ++rg){
        int row = (int)tm * 128 + wm * 64 + mi * 16 + kg * 4 + rg;
        if (row < Mlog){
          float v = acc[mi][ni][rg] + bv;
          if (Cb) Cb[(size_t)row * N + col] = f2bf(v);
          else    Cf[(size_t)row * N + col] = v;
        }
      }
    }
  }
}

// ---------------- grouped encoder: sentinel-dataflow sync ----------------
// 128 blocks = 16 batches x 8 sub-blocks. Whh slice LDS (64KB). Per-step h buffers:
// hbufE[t][b][j], t=0 zeros, t>=1 sentinel-filled; write-once; readers poll data.
__global__ __launch_bounds__(256) void k_enc_g(const unsigned short* __restrict__ Whh_bf,
      const float* __restrict__ Xg, unsigned short* __restrict__ enc_bf,
      float* hbufE, float* hbufD, float* cfin){
  __shared__ __align__(16) unsigned short Ws[128 * 256];  // 64 KB
  __shared__ __align__(16) float h_l[256];
  __shared__ float part[256];
  int tid = threadIdx.x, blk = blockIdx.x;
  int b = blk & 15, sub = blk >> 4, j0 = sub * 32;
  int lr = tid >> 1, kh = tid & 1;

  for (int i = 0; i < 16; ++i){
    int id = i * 256 + tid;
    int slr = id >> 5, c = id & 31;
    int R = (slr >> 5) * 256 + j0 + (slr & 31);
    bh8 v = *reinterpret_cast<const bh8*>(Whh_bf + (size_t)R * 256 + c * 8);
    *reinterpret_cast<bh8*>((char*)Ws + slr * 512 + ((c ^ (slr & 31)) << 4)) = v;
  }
  h_l[tid] = 0.f;
  float creg = 0.f;
  int Rr = (lr >> 5) * 256 + j0 + (lr & 31);
  __syncthreads();

  for (int t = 0; t < 128; ++t){
    // h_t: own 32 values already local; poll others (data-as-flag)
    if (t > 0 && (tid >> 5) != sub)
      h_l[tid] = pollf((const unsigned int*)hbufE + (size_t)t * 4096 + b * 256 + tid);
    __syncthreads();
    // partial: thread (lr, kh) half-row dot
    {
      float acc = (kh == 0) ? Xg[(size_t)(b * 128 + t) * 1024 + Rr] : 0.f;
#pragma unroll
      for (int ci = 0; ci < 16; ++ci){
        int chunk = kh * 16 + ci;
        U8 w; w.v = *reinterpret_cast<const bh8*>((char*)Ws + lr * 512 + ((chunk ^ (lr & 31)) << 4));
        float4 ha = *(const float4*)(h_l + chunk * 8);
        float4 hb = *(const float4*)(h_l + chunk * 8 + 4);
        acc += ha.x*bf2f(w.u[0]) + ha.y*bf2f(w.u[1]) + ha.z*bf2f(w.u[2]) + ha.w*bf2f(w.u[3]);
        acc += hb.x*bf2f(w.u[4]) + hb.y*bf2f(w.u[5]) + hb.z*bf2f(w.u[6]) + hb.w*bf2f(w.u[7]);
      }
      part[tid] = acc;
    }
    __syncthreads();
    if (tid < 32){
      float gi = part[tid*2]      + part[tid*2 + 1];
      float gf = part[(32+tid)*2] + part[(32+tid)*2 + 1];
      float gg = part[(64+tid)*2] + part[(64+tid)*2 + 1];
      float go = part[(96+tid)*2] + part[(96+tid)*2 + 1];
      float c = sigm(gf) * creg + sigm(gi) * tanhf(gg);
      float h = sigm(go) * tanhf(c);
      creg = c;
      int j = j0 + tid;
      h_l[j] = h;                                   // self: LDS-local for next step
      if (t < 127){
        __hip_atomic_store((unsigned int*)hbufE + (size_t)(t + 1) * 4096 + b * 256 + j,
                           __builtin_bit_cast(unsigned int, h), __ATOMIC_RELAXED, __HIP_MEMORY_SCOPE_AGENT);
      } else {
        hbufD[b * 256 + j] = h;                     // kernel boundary orders this
        cfin[b * 256 + j] = c;
      }
      enc_bf[(size_t)(b * 128 + t) * 256 + j] = f2bf(h);
    }
  }
}

// ---------------- grouped decoder: sentinel-dataflow sync ----------------
// hbufD[t][b][j]: t=0 from encoder (plain), t>=1 sentinel. scoreG[t][b][s] sentinel.
__global__ __launch_bounds__(256) void k_dec_g(const unsigned short* __restrict__ Whh_bf,
      const float* __restrict__ Xd, const unsigned short* __restrict__ KW,
      const unsigned short* __restrict__ VWWT, const float* __restrict__ sb,
      float* hbufD, const float* __restrict__ cfin, float* scoreG,
      unsigned short* __restrict__ Hs){
  __shared__ __align__(16) unsigned short Ws[128 * 256];   // 64 KB
  __shared__ __align__(16) unsigned short KW_l[16 * 256];  // 8 KB
  __shared__ __align__(16) unsigned short VW_l[128 * 128]; // 32 KB
  __shared__ __align__(16) float h_l[256];
  __shared__ float part[256];
  __shared__ float sc_l[128];
  __shared__ float at_l[128];
  __shared__ float red0, red1;
  int tid = threadIdx.x, blk = blockIdx.x;
  int b = blk & 15, sub = blk >> 4, j0 = sub * 32;
  int lr = tid >> 1, kh = tid & 1;

  for (int i = 0; i < 16; ++i){
    int id = i * 256 + tid;
    int slr = id >> 5, c = id & 31;
    int R = (slr >> 5) * 256 + j0 + (slr & 31);
    bh8 v = *reinterpret_cast<const bh8*>(Whh_bf + (size_t)R * 256 + c * 8);
    *reinterpret_cast<bh8*>((char*)Ws + slr * 512 + ((c ^ (slr & 31)) << 4)) = v;
  }
  for (int i = 0; i < 2; ++i){
    int id = i * 256 + tid;
    int slr = id >> 5, c = id & 31;
    bh8 v = *reinterpret_cast<const bh8*>(KW + (size_t)(b * 128 + sub * 16 + slr) * 256 + c * 8);
    *reinterpret_cast<bh8*>((char*)KW_l + slr * 512 + (c << 4)) = v;
  }
  for (int i = 0; i < 8; ++i){
    int id = i * 256 + tid;
    int slr = id >> 4, c = id & 15;
    int R = (slr >> 5) * 256 + j0 + (slr & 31);
    bh8 v = *reinterpret_cast<const bh8*>(VWWT + (size_t)R * 2048 + b * 128 + c * 8);
    *reinterpret_cast<bh8*>((char*)VW_l + slr * 256 + ((c ^ (slr & 15)) << 4)) = v;
  }
  float creg = (tid < 32) ? cfin[b * 256 + j0 + tid] : 0.f;
  int Rr = (lr >> 5) * 256 + j0 + (lr & 31);
  __syncthreads();

  for (int t = 0; t < 63; ++t){
    // h_t: t=0 all read (encoder-written); else poll others, own is local
    if (t == 0 || (tid >> 5) != sub)
      h_l[tid] = pollf((const unsigned int*)hbufD + (size_t)t * 4096 + b * 256 + tid);
    __syncthreads();
    // scores partial: thread (ss=tid>>4, kq=tid&15)
    {
      int ss = tid >> 4, kq = tid & 15;
      float a = 0.f;
#pragma unroll
      for (int i = 0; i < 2; ++i){
        U8 ku; ku.v = *reinterpret_cast<const bh8*>((char*)KW_l + ss * 512 + ((kq * 2 + i) << 4));
        const float* hp = h_l + kq * 16 + i * 8;
#pragma unroll
        for (int q = 0; q < 8; ++q) a += hp[q] * bf2f(ku.u[q]);
      }
      part[tid] = a;
    }
    __syncthreads();
    if (tid < 16){
      float s = 0.f;
#pragma unroll
      for (int q = 0; q < 16; ++q) s += part[tid * 16 + q];
      int sidx = sub * 16 + tid;
      s = (s + sb[b * 128 + sidx]) * 0.0625f;
      __hip_atomic_store((unsigned int*)scoreG + (size_t)t * 2048 + b * 128 + sidx,
                         __builtin_bit_cast(unsigned int, s), __ATOMIC_RELAXED, __HIP_MEMORY_SCOPE_AGENT);
    }
    // Whh partial (overlaps other blocks' score phase)
    float wacc = (kh == 0) ? Xd[(size_t)(b * 63 + t) * 1024 + Rr] : 0.f;
#pragma unroll
    for (int ci = 0; ci < 16; ++ci){
      int chunk = kh * 16 + ci;
      U8 w; w.v = *reinterpret_cast<const bh8*>((char*)Ws + lr * 512 + ((chunk ^ (lr & 31)) << 4));
      float4 ha = *(const float4*)(h_l + chunk * 8);
      float4 hb = *(const float4*)(h_l + chunk * 8 + 4);
      wacc += ha.x*bf2f(w.u[0]) + ha.y*bf2f(w.u[1]) + ha.z*bf2f(w.u[2]) + ha.w*bf2f(w.u[3]);
      wacc += hb.x*bf2f(w.u[4]) + hb.y*bf2f(w.u[5]) + hb.z*bf2f(w.u[6]) + hb.w*bf2f(w.u[7]);
    }
    __syncthreads();           // score-reduce reads of part[] done
    part[tid] = wacc;
    // poll full score row (data-as-flag)
    if (tid < 128)
      sc_l[tid] = pollf((const unsigned int*)scoreG + (size_t)t * 2048 + b * 128 + tid);
    __syncthreads();
    if (tid < 64){
      float m = fmaxf(sc_l[tid], sc_l[tid + 64]);
      for (int o = 32; o; o >>= 1) m = fmaxf(m, __shfl_xor(m, o));
      if (tid == 0) red0 = m;
    }
    __syncthreads();
    if (tid < 128) sc_l[tid] = __expf(sc_l[tid] - red0);
    __syncthreads();
    if (tid < 64){
      float s = sc_l[tid] + sc_l[tid + 64];
      for (int o = 32; o; o >>= 1) s += __shfl_xor(s, o);
      if (tid == 0) red1 = s;
    }
    __syncthreads();
    if (tid < 128) at_l[tid] = sc_l[tid] / red1;
    __syncthreads();
    // VWW partial
    {
      float acc = 0.f;
#pragma unroll
      for (int sc8 = 0; sc8 < 8; ++sc8){
        int chunk = kh * 8 + sc8;
        U8 vv; vv.v = *reinterpret_cast<const bh8*>((char*)VW_l + lr * 256 + ((chunk ^ (lr & 15)) << 4));
        float4 aa = *(const float4*)(at_l + chunk * 8);
        float4 ab = *(const float4*)(at_l + chunk * 8 + 4);
        acc += aa.x*bf2f(vv.u[0]) + aa.y*bf2f(vv.u[1]) + aa.z*bf2f(vv.u[2]) + aa.w*bf2f(vv.u[3]);
        acc += ab.x*bf2f(vv.u[4]) + ab.y*bf2f(vv.u[5]) + ab.z*bf2f(vv.u[6]) + ab.w*bf2f(vv.u[7]);
      }
      part[tid] += acc;
    }
    __syncthreads();
    if (tid < 32){
      float gi = part[tid*2]      + part[tid*2 + 1];
      float gf = part[(32+tid)*2] + part[(32+tid)*2 + 1];
      float gg = part[(64+tid)*2] + part[(64+tid)*2 + 1];
      float go = part[(96+tid)*2] + part[(96+tid)*2 + 1];
      float c = sigm(gf) * creg + sigm(gi) * tanhf(gg);
      float h = sigm(go) * tanhf(c);
      creg = c;
      int j = j0 + tid;
      h_l[j] = h;
      __hip_atomic_store((unsigned int*)hbufD + (size_t)(t + 1) * 4096 + b * 256 + j,
                         __builtin_bit_cast(unsigned int, h), __ATOMIC_RELAXED, __HIP_MEMORY_SCOPE_AGENT);
      Hs[(size_t)(b * 63 + t) * 256 + j] = f2bf(h);
    }
  }
}

// ---------------- host ----------------
extern "C" void kernel_launch(void* const* d_in, const int* in_sizes, int n_in,
                              void* d_out, int out_size, void* d_ws, size_t ws_size,
                              hipStream_t stream){
  const int expect[20] = {2048, 1024, 8192000, 262144, 262144, 1024, 8192000,
                          65536, 256, 65536, 256, 65536, 256, 65536, 256,
                          524288, 262144, 1024, 8192000, 32000};
  if (n_in != 20 || out_size != 32256000) return;
  for (int i = 0; i < 20; ++i) if (in_sizes[i] != expect[i]) return;

  const int*   input_seq  = (const int*)  d_in[0];
  const int*   target_seq = (const int*)  d_in[1];
  const float* enc_emb    = (const float*)d_in[2];
  const float* enc_Wih    = (const float*)d_in[3];
  const float* enc_Whh    = (const float*)d_in[4];
  const float* enc_b      = (const float*)d_in[5];
  const float* dec_emb    = (const float*)d_in[6];
  const float* Wq         = (const float*)d_in[7];
  const float* bq         = (const float*)d_in[8];
  const float* Wk         = (const float*)d_in[9];
  const float* bk         = (const float*)d_in[10];
  const float* Wv         = (const float*)d_in[11];
  const float* bv         = (const float*)d_in[12];
  const float* Wo         = (const float*)d_in[13];
  const float* bo         = (const float*)d_in[14];
  const float* dec_Wih    = (const float*)d_in[15];
  const float* dec_Whh    = (const float*)d_in[16];
  const float* dec_b      = (const float*)d_in[17];
  const float* Wout       = (const float*)d_in[18];
  const float* bout       = (const float*)d_in[19];

  char* p = (char*)d_ws;
  auto alloc = [&](size_t sz)->char*{ char* r = p; p += (sz + 255) & ~(size_t)255; return r; };

  // ---- zero zone ----
  unsigned short* Hs     = (unsigned short*)alloc((size_t)1024 * 256 * 2);
  size_t zsz = (size_t)(p - (char*)d_ws);
  // ---- sentinel (0xFF) zone: per-step exchange buffers, write-once ----
  float*          hbufE  = (float*)         alloc((size_t)128 * 4096 * 4);  // [t][b][j]
  float*          hbufD  = (float*)         alloc((size_t)64 * 4096 * 4);
  float*          scoreG = (float*)         alloc((size_t)63 * 2048 * 4);   // [t][b][s]
  size_t ffend = (size_t)(p - (char*)d_ws);
  // ---- working buffers (fully written before read) ----
  float*          cfin   = (float*)          alloc(16 * 256 * 4);
  unsigned short* src_bf  = (unsigned short*)alloc((size_t)2048 * 256 * 2);
  unsigned short* tok_bf  = (unsigned short*)alloc((size_t)1024 * 256 * 2);
  unsigned short* wih_bf  = (unsigned short*)alloc((size_t)1024 * 256 * 2);
  unsigned short* wxd_bf  = (unsigned short*)alloc((size_t)1024 * 256 * 2);
  unsigned short* wout_bf = (unsigned short*)alloc((size_t)32000 * 256 * 2);
  unsigned short* whhE_bf = (unsigned short*)alloc((size_t)1024 * 256 * 2);
  unsigned short* whhD_bf = (unsigned short*)alloc((size_t)1024 * 256 * 2);
  float*          Gf      = (float*)         alloc((size_t)1024 * 256 * 4);
  unsigned short* A3bf    = (unsigned short*)alloc((size_t)256 * 256 * 2);
  unsigned short* A2bf    = (unsigned short*)alloc((size_t)1024 * 256 * 2);
  float*          c3f     = (float*)         alloc(256 * 4);
  float*          c4f     = (float*)         alloc(256 * 4);
  float*          c5f     = (float*)         alloc(256);
  float*          xdb     = (float*)         alloc(1024 * 4);
  float*          Xg      = (float*)         alloc((size_t)2048 * 1024 * 4);
  float*          Xd      = (float*)         alloc((size_t)1024 * 1024 * 4);
  unsigned short* enc_bf  = (unsigned short*)alloc((size_t)2048 * 256 * 2);
  unsigned short* KWb     = (unsigned short*)alloc((size_t)2048 * 256 * 2);
  unsigned short* VWWT    = (unsigned short*)alloc((size_t)1024 * 2048 * 2);
  float*          sbf     = (float*)         alloc(2048 * 4);
  if ((size_t)(p - (char*)d_ws) > ws_size) return;

  hipMemsetAsync(d_ws, 0, zsz, stream);
  hipMemsetAsync((char*)d_ws + zsz, 0xFF, ffend - zsz, stream);   // sentinel fill
  hipMemsetAsync(hbufE, 0, 4096 * 4, stream);                     // h_0 = zeros

  // prep
  k_gather_src<<<2048, 64, 0, stream>>>(input_seq, enc_emb, src_bf);
  k_gather_tok<<<1024, 64, 0, stream>>>(target_seq, dec_emb, tok_bf);
  k_conv<<<1024, 256, 0, stream>>>(enc_Wih, wih_bf, 1024, 256);
  k_conv<<<1024, 256, 0, stream>>>(dec_Wih, wxd_bf, 1024, 512);
  k_conv<<<1024, 256, 0, stream>>>(Wout,    wout_bf, 32000, 256);
  k_conv<<<1024, 256, 0, stream>>>(enc_Whh, whhE_bf, 1024, 256);
  k_conv<<<1024, 256, 0, stream>>>(dec_Whh, whhD_bf, 1024, 256);

  // folds
  k_fold<<<(1024*256+255)/256, 256, 0, stream>>>(dec_Wih,256,512,1, Wo,0,1,256, nullptr, Gf,nullptr, 1024,256);
  k_fold<<<(256*256+255)/256,  256, 0, stream>>>(Wq,0,1,256,        Wk,0,1,256, nullptr, nullptr,A3bf, 256,256);
  k_fold<<<1,                  256, 0, stream>>>(bk,0,0,1,          Wq,0,1,256, nullptr, c3f,nullptr, 1,256);
  k_fold<<<1,                  256, 0, stream>>>(bq,0,0,1,          Wk,0,1,256, nullptr, c4f,nullptr, 1,256);
  k_fold<<<1,                  256, 0, stream>>>(bq,0,0,1,          bk,0,0,1,   nullptr, c5f,nullptr, 1,1);
  k_fold<<<(1024+255)/256,     256, 0, stream>>>(dec_Wih,256,512,1, bo,0,0,1,   dec_b,   xdb,nullptr, 1024,1);
  k_fold<<<(1024*256+255)/256, 256, 0, stream>>>(Gf,0,256,1,        Wv,0,1,256, nullptr, nullptr,A2bf, 1024,256);
  k_fold<<<(1024+255)/256,     256, 0, stream>>>(Gf,0,256,1,        bv,0,0,1,   xdb,     xdb,nullptr, 1024,1);

  // big parallel GEMMs
  k_gemm<<<dim3(8, 16),  256, 0, stream>>>(src_bf, wih_bf, enc_b, Xg, nullptr, 2048, 1024);
  k_gemm<<<dim3(8, 8),   256, 0, stream>>>(tok_bf, wxd_bf, xdb,   Xd, nullptr, 1024, 1024);

  // encoder: sentinel-dataflow, no barriers
  k_enc_g<<<128, 256, 0, stream>>>(whhE_bf, Xg, enc_bf, hbufE, hbufD, cfin);

  // attention precomputes
  k_gemm<<<dim3(2, 16),  256, 0, stream>>>(enc_bf, A3bf, c3f, nullptr, KWb,  2048, 256);
  k_gemm<<<dim3(16, 8),  256, 0, stream>>>(A2bf, enc_bf, nullptr, nullptr, VWWT, 1024, 2048);
  k_sb<<<8, 256, 0, stream>>>(enc_bf, c4f, c5f, sbf);

  // decoder: sentinel-dataflow, no barriers
  k_dec_g<<<128, 256, 0, stream>>>(whhD_bf, Xd, KWb, VWWT, sbf, hbufD, cfin, scoreG, Hs);

  // logits -> FP32 d_out
  k_gemm<<<dim3(250, 8), 256, 0, stream>>>(Hs, wout_bf, bout, (float*)d_out, nullptr, 1008, 32000);
}

// Round 10
// 705.647 us; speedup vs baseline: 5.4679x; 1.2211x over previous
//
#include <hip/hip_runtime.h>

// ---------------- types / helpers ----------------
typedef short bh8 __attribute__((ext_vector_type(8)));     // 8 x bf16 raw
typedef float f32x4 __attribute__((ext_vector_type(4)));

#define DEVI __device__ __forceinline__

union U8 { bh8 v; unsigned short u[8]; };

DEVI float bf2f(unsigned short u){
  unsigned int x = ((unsigned int)u) << 16;
  return __builtin_bit_cast(float, x);
}
DEVI unsigned short f2bf(float f){
  unsigned int u = __builtin_bit_cast(unsigned int, f);
  u += 0x7fffu + ((u >> 16) & 1u);
  return (unsigned short)(u >> 16);
}
DEVI float sigm(float x){ return 1.0f/(1.0f + __expf(-x)); }

DEVI f32x4 MFMA(bh8 a, bh8 b, f32x4 c){
  return __builtin_amdgcn_mfma_f32_16x16x32_bf16(a, b, c, 0, 0, 0);
}

// data-as-flag poll: location written once per call; sentinel = 0xFFFFFFFF (NaN, unreachable)
DEVI float pollf(const unsigned int* pnt){
  unsigned int v; int it = 0;
  do { v = __hip_atomic_load(pnt, __ATOMIC_RELAXED, __HIP_MEMORY_SCOPE_AGENT); }
  while (v == 0xFFFFFFFFu && ++it < (1 << 24));
  return __builtin_bit_cast(float, v);
}

// ---------------- fused prep device bodies (verbatim logic) ----------------
DEVI void conv_dev(const float* src, unsigned short* dst, int rows, int rstride,
                   int lblk, int nblk){
  int tid = threadIdx.x;
  size_t n = (size_t)rows * 128;      // pairs
  for (size_t i = (size_t)lblk * 256 + tid; i < n; i += (size_t)nblk * 256){
    size_t r = i >> 7; int c = ((int)(i & 127)) * 2;
    const float* s = src + r * (size_t)rstride + c;
    unsigned int hp = (unsigned int)f2bf(s[0]) | ((unsigned int)f2bf(s[1]) << 16);
    *(unsigned int*)(dst + r * 256 + c) = hp;
  }
}

DEVI void fold_dev(const float* A, int offA, int sAm, int sAk,
                   const float* Bm, int offB, int sBn, int sBk,
                   const float* addM, float* Cf, unsigned short* Cb,
                   int M, int N, int lblk, int nblk){
  int tid = threadIdx.x;
  for (int i = lblk * 256 + tid; i < M * N; i += nblk * 256){
    int m = i / N, n = i - m * N;
    const float* a = A + offA + (size_t)m * sAm;
    const float* b = Bm + offB + (size_t)n * sBn;
    float acc = 0.f;
    for (int k = 0; k < 256; ++k) acc += a[(size_t)k * sAk] * b[(size_t)k * sBk];
    if (addM) acc += addM[m];
    if (Cf) Cf[i] = acc;
    if (Cb) Cb[i] = f2bf(acc);
  }
}

// ---------------- prep mega-kernel A: gathers + convs + independent folds ----------------
__global__ __launch_bounds__(256) void k_prepA(const int* input_seq, const int* target_seq,
      const float* enc_emb, const float* dec_emb,
      const float* enc_Wih, const float* dec_Wih, const float* Wout,
      const float* enc_Whh, const float* dec_Whh,
      const float* Wq, const float* Wk, const float* bq, const float* bk,
      const float* Wo, const float* bo, const float* dec_b,
      unsigned short* src_bf, unsigned short* tok_bf,
      unsigned short* wih_bf, unsigned short* wxd_bf, unsigned short* wout_bf,
      unsigned short* whhE_bf, unsigned short* whhD_bf,
      float* Gf, unsigned short* A3bf, float* c3f, float* c4f, float* c5f, float* xdb){
  int blk = blockIdx.x, tid = threadIdx.x;
  if (blk < 512){                               // gather src: 4 rows/blk
    for (int r = 0; r < 4; ++r){
      int m = blk * 4 + r;
      int idx = input_seq[m];
      src_bf[(size_t)m * 256 + tid] = f2bf(enc_emb[(size_t)idx * 256 + tid]);
    }
  } else if (blk < 768){                        // gather tok
    int lb = blk - 512;
    for (int r = 0; r < 4; ++r){
      int m = lb * 4 + r;
      if (m < 1008){
        int bb = m / 63, t = m - bb * 63;
        int idx = target_seq[bb * 64 + t];
        tok_bf[(size_t)m * 256 + tid] = f2bf(dec_emb[(size_t)idx * 256 + tid]);
      } else tok_bf[(size_t)m * 256 + tid] = 0;
    }
  }
  else if (blk < 896)  conv_dev(enc_Wih, wih_bf, 1024, 256, blk - 768, 128);
  else if (blk < 1024) conv_dev(dec_Wih, wxd_bf, 1024, 512, blk - 896, 128);
  else if (blk < 2048) conv_dev(Wout,    wout_bf, 32000, 256, blk - 1024, 1024);
  else if (blk < 2176) conv_dev(enc_Whh, whhE_bf, 1024, 256, blk - 2048, 128);
  else if (blk < 2304) conv_dev(dec_Whh, whhD_bf, 1024, 256, blk - 2176, 128);
  else if (blk < 3328) fold_dev(dec_Wih,256,512,1, Wo,0,1,256, nullptr, Gf,nullptr, 1024,256, blk - 2304, 1024);
  else if (blk < 3584) fold_dev(Wq,0,1,256,        Wk,0,1,256, nullptr, nullptr,A3bf, 256,256, blk - 3328, 256);
  else if (blk == 3584) fold_dev(bk,0,0,1, Wq,0,1,256, nullptr, c3f,nullptr, 1,256, 0, 1);
  else if (blk == 3585) fold_dev(bq,0,0,1, Wk,0,1,256, nullptr, c4f,nullptr, 1,256, 0, 1);
  else if (blk == 3586) fold_dev(bq,0,0,1, bk,0,0,1,   nullptr, c5f,nullptr, 1,1,   0, 1);
  else                  fold_dev(dec_Wih,256,512,1, bo,0,0,1, dec_b, xdb,nullptr, 1024,1, blk - 3587, 4);
}

// ---------------- prep mega-kernel B: folds depending on Gf ----------------
__global__ __launch_bounds__(256) void k_prepB(const float* Gf, const float* Wv,
      const float* bv, unsigned short* A2bf, float* xdb){
  int blk = blockIdx.x;
  if (blk < 512) fold_dev(Gf,0,256,1, Wv,0,1,256, nullptr, nullptr,A2bf, 1024,256, blk, 512);
  else           fold_dev(Gf,0,256,1, bv,0,0,1,   xdb,     xdb,nullptr, 1024,1,   blk - 512, 4);
}

// ---------------- bf16 MFMA GEMM tile (validated body), as device fn ----------------
DEVI void gemm_tile(const unsigned short* __restrict__ A,
      const unsigned short* __restrict__ Bw, const float* __restrict__ bias,
      float* __restrict__ Cf, unsigned short* __restrict__ Cb, int Mlog, int N,
      int tmi, int tni, unsigned short* lA, unsigned short* lB){
  int tid = threadIdx.x;
  int lane = tid & 63, wave = tid >> 6;
  int wm = wave >> 1, wn = wave & 1;
  int kg = lane >> 4, l15 = lane & 15;
  size_t tm = tmi, tn = tni;
  f32x4 acc[4][4];
#pragma unroll
  for (int i = 0; i < 4; ++i)
#pragma unroll
    for (int j = 0; j < 4; ++j) acc[i][j] = (f32x4){0.f, 0.f, 0.f, 0.f};

  for (int ks = 0; ks < 8; ++ks){
    __syncthreads();
#pragma unroll
    for (int i = 0; i < 2; ++i){
      int slot = i * 256 + tid;
      int r = slot >> 2, sg = slot & 3;
      bh8 va = *reinterpret_cast<const bh8*>(A + (tm * 128 + r) * 256 + ks * 32 + sg * 8);
      *reinterpret_cast<bh8*>((char*)lA + r * 64 + ((sg ^ (r & 3)) << 4)) = va;
      bh8 vb = *reinterpret_cast<const bh8*>(Bw + (tn * 128 + r) * 256 + ks * 32 + sg * 8);
      *reinterpret_cast<bh8*>((char*)lB + r * 64 + ((sg ^ (r & 3)) << 4)) = vb;
    }
    __syncthreads();
    bh8 af[4], bfr[4];
#pragma unroll
    for (int mi = 0; mi < 4; ++mi){
      int r = wm * 64 + mi * 16 + l15;
      af[mi] = *reinterpret_cast<const bh8*>((char*)lA + r * 64 + ((kg ^ (r & 3)) << 4));
    }
#pragma unroll
    for (int ni = 0; ni < 4; ++ni){
      int r = wn * 64 + ni * 16 + l15;
      bfr[ni] = *reinterpret_cast<const bh8*>((char*)lB + r * 64 + ((kg ^ (r & 3)) << 4));
    }
#pragma unroll
    for (int mi = 0; mi < 4; ++mi)
#pragma unroll
      for (int ni = 0; ni < 4; ++ni)
        acc[mi][ni] = MFMA(af[mi], bfr[ni], acc[mi][ni]);
  }
#pragma unroll
  for (int ni = 0; ni < 4; ++ni){
    int col = (int)tn * 128 + wn * 64 + ni * 16 + l15;
    float bv = bias ? bias[col] : 0.f;
#pragma unroll
    for (int mi = 0; mi < 4; ++mi){
#pragma unroll
      for (int rg = 0; rg < 4; ++rg){
        int row = (int)tm * 128 + wm * 64 + mi * 16 + kg * 4 + rg;
        if (row < Mlog){
          float v = acc[mi][ni][rg] + bv;
          if (Cb) Cb[(size_t)row * N + col] = f2bf(v);
          else    Cf[(size_t)row * N + col] = v;
        }
      }
    }
  }
}

// standalone GEMM (logits)
__global__ __launch_bounds__(256) void k_gemm(const unsigned short* __restrict__ A,
      const unsigned short* __restrict__ Bw, const float* __restrict__ bias,
      float* __restrict__ Cf, unsigned short* __restrict__ Cb, int Mlog, int N){
  __shared__ __align__(16) unsigned short lA[128 * 32];
  __shared__ __align__(16) unsigned short lB[128 * 32];
  gemm_tile(A, Bw, bias, Cf, Cb, Mlog, N, blockIdx.y, blockIdx.x, lA, lB);
}

// fused Xg + Xd GEMMs: 192 blocks
__global__ __launch_bounds__(256) void k_gemmAB(const unsigned short* src_bf,
      const unsigned short* wih_bf, const float* enc_b, float* Xg,
      const unsigned short* tok_bf, const unsigned short* wxd_bf, const float* xdb, float* Xd){
  __shared__ __align__(16) unsigned short lA[128 * 32];
  __shared__ __align__(16) unsigned short lB[128 * 32];
  int blk = blockIdx.x;
  if (blk < 128) gemm_tile(src_bf, wih_bf, enc_b, Xg, nullptr, 2048, 1024, blk >> 3, blk & 7, lA, lB);
  else { int l = blk - 128; gemm_tile(tok_bf, wxd_bf, xdb, Xd, nullptr, 1024, 1024, l >> 3, l & 7, lA, lB); }
}

// fused post-encoder: KW gemm (32) + VWWT gemm (128) + sb (8): 168 blocks
__global__ __launch_bounds__(256) void k_gemmPost(const unsigned short* enc_bf,
      const unsigned short* A3bf, const float* c3f, unsigned short* KWb,
      const unsigned short* A2bf, unsigned short* VWWT,
      const float* c4f, const float* c5f, float* sbf){
  __shared__ __align__(16) unsigned short lA[128 * 32];
  __shared__ __align__(16) unsigned short lB[128 * 32];
  int blk = blockIdx.x, tid = threadIdx.x;
  if (blk < 32) gemm_tile(enc_bf, A3bf, c3f, nullptr, KWb, 2048, 256, blk >> 1, blk & 1, lA, lB);
  else if (blk < 160){ int l = blk - 32; gemm_tile(A2bf, enc_bf, nullptr, nullptr, VWWT, 1024, 2048, l >> 4, l & 15, lA, lB); }
  else {
    int m = (blk - 160) * 256 + tid;
    const unsigned short* e = enc_bf + (size_t)m * 256;
    float a = 0.f;
    for (int k = 0; k < 256; ++k) a += bf2f(e[k]) * c4f[k];
    sbf[m] = a + c5f[0];
  }
}

// ---------------- grouped encoder: sentinel-dataflow (round-9 validated) ----------------
__global__ __launch_bounds__(256) void k_enc_g(const unsigned short* __restrict__ Whh_bf,
      const float* __restrict__ Xg, unsigned short* __restrict__ enc_bf,
      float* hbufE, float* hbufD, float* cfin){
  __shared__ __align__(16) unsigned short Ws[128 * 256];  // 64 KB
  __shared__ __align__(16) float h_l[256];
  __shared__ float part[256];
  int tid = threadIdx.x, blk = blockIdx.x;
  int b = blk & 15, sub = blk >> 4, j0 = sub * 32;
  int lr = tid >> 1, kh = tid & 1;

  for (int i = 0; i < 16; ++i){
    int id = i * 256 + tid;
    int slr = id >> 5, c = id & 31;
    int R = (slr >> 5) * 256 + j0 + (slr & 31);
    bh8 v = *reinterpret_cast<const bh8*>(Whh_bf + (size_t)R * 256 + c * 8);
    *reinterpret_cast<bh8*>((char*)Ws + slr * 512 + ((c ^ (slr & 31)) << 4)) = v;
  }
  h_l[tid] = 0.f;
  float creg = 0.f;
  int Rr = (lr >> 5) * 256 + j0 + (lr & 31);
  __syncthreads();

  for (int t = 0; t < 128; ++t){
    if (t > 0 && (tid >> 5) != sub)
      h_l[tid] = pollf((const unsigned int*)hbufE + (size_t)t * 4096 + b * 256 + tid);
    __syncthreads();
    {
      float acc = (kh == 0) ? Xg[(size_t)(b * 128 + t) * 1024 + Rr] : 0.f;
#pragma unroll
      for (int ci = 0; ci < 16; ++ci){
        int chunk = kh * 16 + ci;
        U8 w; w.v = *reinterpret_cast<const bh8*>((char*)Ws + lr * 512 + ((chunk ^ (lr & 31)) << 4));
        float4 ha = *(const float4*)(h_l + chunk * 8);
        float4 hb = *(const float4*)(h_l + chunk * 8 + 4);
        acc += ha.x*bf2f(w.u[0]) + ha.y*bf2f(w.u[1]) + ha.z*bf2f(w.u[2]) + ha.w*bf2f(w.u[3]);
        acc += hb.x*bf2f(w.u[4]) + hb.y*bf2f(w.u[5]) + hb.z*bf2f(w.u[6]) + hb.w*bf2f(w.u[7]);
      }
      part[tid] = acc;
    }
    __syncthreads();
    if (tid < 32){
      float gi = part[tid*2]      + part[tid*2 + 1];
      float gf = part[(32+tid)*2] + part[(32+tid)*2 + 1];
      float gg = part[(64+tid)*2] + part[(64+tid)*2 + 1];
      float go = part[(96+tid)*2] + part[(96+tid)*2 + 1];
      float c = sigm(gf) * creg + sigm(gi) * tanhf(gg);
      float h = sigm(go) * tanhf(c);
      creg = c;
      int j = j0 + tid;
      h_l[j] = h;
      if (t < 127){
        __hip_atomic_store((unsigned int*)hbufE + (size_t)(t + 1) * 4096 + b * 256 + j,
                           __builtin_bit_cast(unsigned int, h), __ATOMIC_RELAXED, __HIP_MEMORY_SCOPE_AGENT);
      } else {
        hbufD[b * 256 + j] = h;
        cfin[b * 256 + j] = c;
      }
      enc_bf[(size_t)(b * 128 + t) * 256 + j] = f2bf(h);
    }
  }
}

// ---------------- one-hop decoder: full KW local, redundant softmax, VWW in regs ----------------
// 128 blocks = 16 batches x 8 sub-blocks; LDS = KW 64KB + Whh-slice 64KB (~131KB total)
__global__ __launch_bounds__(256) void k_dec_g(const unsigned short* __restrict__ Whh_bf,
      const float* __restrict__ Xd, const unsigned short* __restrict__ KW,
      const unsigned short* __restrict__ VWWT, const float* __restrict__ sb,
      float* hbufD, const float* __restrict__ cfin,
      unsigned short* __restrict__ Hs){
  __shared__ __align__(16) unsigned short KW_l[128 * 256];  // 64 KB
  __shared__ __align__(16) unsigned short Ws[128 * 256];    // 64 KB
  __shared__ __align__(16) float h_l[256];
  __shared__ float part[256];
  __shared__ float sc_l[128];
  __shared__ float at_l[128];
  __shared__ float red0, red1;
  int tid = threadIdx.x, blk = blockIdx.x;
  int b = blk & 15, sub = blk >> 4, j0 = sub * 32;
  int ss = tid >> 1, kh = tid & 1;      // score mapping (also gates: lr=ss, kh2=kh)
  int lr = ss;

  // stage KW full (swizzled)
  for (int i = 0; i < 16; ++i){
    int id = i * 256 + tid;
    int row = id >> 5, c = id & 31;
    bh8 v = *reinterpret_cast<const bh8*>(KW + (size_t)(b * 128 + row) * 256 + c * 8);
    *reinterpret_cast<bh8*>((char*)KW_l + row * 512 + ((c ^ (row & 31)) << 4)) = v;
  }
  // stage Whh slice: 128 gate rows R=(row>>5)*256 + j0 + (row&31)
  for (int i = 0; i < 16; ++i){
    int id = i * 256 + tid;
    int row = id >> 5, c = id & 31;
    int R = (row >> 5) * 256 + j0 + (row & 31);
    bh8 v = *reinterpret_cast<const bh8*>(Whh_bf + (size_t)R * 256 + c * 8);
    *reinterpret_cast<bh8*>((char*)Ws + row * 512 + ((c ^ (row & 31)) << 4)) = v;
  }
  // VWW slice into registers (step-invariant): thread (lr, kh) -> row lr, s-range kh*64..+64
  int Rr = (lr >> 5) * 256 + j0 + (lr & 31);
  U8 vw[8];
#pragma unroll
  for (int ci = 0; ci < 8; ++ci)
    vw[ci].v = *reinterpret_cast<const bh8*>(VWWT + (size_t)Rr * 2048 + b * 128 + kh * 64 + ci * 8);
  float sbreg = (tid < 128) ? sb[b * 128 + tid] : 0.f;
  float creg = (tid < 32) ? cfin[b * 256 + j0 + tid] : 0.f;
  __syncthreads();

  for (int t = 0; t < 63; ++t){
    float xdreg = (kh == 0) ? Xd[(size_t)(b * 63 + t) * 1024 + Rr] : 0.f;  // overlaps poll
    if (t == 0 || (tid >> 5) != sub)
      h_l[tid] = pollf((const unsigned int*)hbufD + (size_t)t * 4096 + b * 256 + tid);
    __syncthreads();
    // scores partial: thread (ss, kh) half-row of KW row ss
    {
      float a = 0.f;
#pragma unroll
      for (int i = 0; i < 16; ++i){
        int ch = kh * 16 + i;
        U8 ku; ku.v = *reinterpret_cast<const bh8*>((char*)KW_l + ss * 512 + ((ch ^ (ss & 31)) << 4));
        const float* hp = h_l + ch * 8;
#pragma unroll
        for (int q = 0; q < 8; ++q) a += hp[q] * bf2f(ku.u[q]);
      }
      part[tid] = a;
    }
    __syncthreads();
    if (tid < 128) sc_l[tid] = (part[2 * tid] + part[2 * tid + 1] + sbreg) * 0.0625f;
    __syncthreads();
    if (tid < 64){
      float m = fmaxf(sc_l[tid], sc_l[tid + 64]);
      for (int o = 32; o; o >>= 1) m = fmaxf(m, __shfl_xor(m, o));
      if (tid == 0) red0 = m;
    }
    __syncthreads();
    if (tid < 128) sc_l[tid] = __expf(sc_l[tid] - red0);
    __syncthreads();
    if (tid < 64){
      float s = sc_l[tid] + sc_l[tid + 64];
      for (int o = 32; o; o >>= 1) s += __shfl_xor(s, o);
      if (tid == 0) red1 = s;
    }
    __syncthreads();
    if (tid < 128) at_l[tid] = sc_l[tid] / red1;
    __syncthreads();
    // gates partial: thread (lr, kh): Whh half-row + VWW half-row (regs)
    {
      float acc = xdreg;
#pragma unroll
      for (int ci = 0; ci < 16; ++ci){
        int ch = kh * 16 + ci;
        U8 w; w.v = *reinterpret_cast<const bh8*>((char*)Ws + lr * 512 + ((ch ^ (lr & 31)) << 4));
        float4 ha = *(const float4*)(h_l + ch * 8);
        float4 hb = *(const float4*)(h_l + ch * 8 + 4);
        acc += ha.x*bf2f(w.u[0]) + ha.y*bf2f(w.u[1]) + ha.z*bf2f(w.u[2]) + ha.w*bf2f(w.u[3]);
        acc += hb.x*bf2f(w.u[4]) + hb.y*bf2f(w.u[5]) + hb.z*bf2f(w.u[6]) + hb.w*bf2f(w.u[7]);
      }
#pragma unroll
      for (int ci = 0; ci < 8; ++ci){
        const float* ap = at_l + kh * 64 + ci * 8;
#pragma unroll
        for (int q = 0; q < 8; ++q) acc += ap[q] * bf2f(vw[ci].u[q]);
      }
      part[tid] = acc;
    }
    __syncthreads();
    if (tid < 32){
      float gi = part[tid*2]      + part[tid*2 + 1];
      float gf = part[(32+tid)*2] + part[(32+tid)*2 + 1];
      float gg = part[(64+tid)*2] + part[(64+tid)*2 + 1];
      float go = part[(96+tid)*2] + part[(96+tid)*2 + 1];
      float c = sigm(gf) * creg + sigm(gi) * tanhf(gg);
      float h = sigm(go) * tanhf(c);
      creg = c;
      int j = j0 + tid;
      h_l[j] = h;
      __hip_atomic_store((unsigned int*)hbufD + (size_t)(t + 1) * 4096 + b * 256 + j,
                         __builtin_bit_cast(unsigned int, h), __ATOMIC_RELAXED, __HIP_MEMORY_SCOPE_AGENT);
      Hs[(size_t)(b * 63 + t) * 256 + j] = f2bf(h);
    }
    __syncthreads();
  }
}

// ---------------- host ----------------
extern "C" void kernel_launch(void* const* d_in, const int* in_sizes, int n_in,
                              void* d_out, int out_size, void* d_ws, size_t ws_size,
                              hipStream_t stream){
  const int expect[20] = {2048, 1024, 8192000, 262144, 262144, 1024, 8192000,
                          65536, 256, 65536, 256, 65536, 256, 65536, 256,
                          524288, 262144, 1024, 8192000, 32000};
  if (n_in != 20 || out_size != 32256000) return;
  for (int i = 0; i < 20; ++i) if (in_sizes[i] != expect[i]) return;

  const int*   input_seq  = (const int*)  d_in[0];
  const int*   target_seq = (const int*)  d_in[1];
  const float* enc_emb    = (const float*)d_in[2];
  const float* enc_Wih    = (const float*)d_in[3];
  const float* enc_Whh    = (const float*)d_in[4];
  const float* enc_b      = (const float*)d_in[5];
  const float* dec_emb    = (const float*)d_in[6];
  const float* Wq         = (const float*)d_in[7];
  const float* bq         = (const float*)d_in[8];
  const float* Wk         = (const float*)d_in[9];
  const float* bk         = (const float*)d_in[10];
  const float* Wv         = (const float*)d_in[11];
  const float* bv         = (const float*)d_in[12];
  const float* Wo         = (const float*)d_in[13];
  const float* bo         = (const float*)d_in[14];
  const float* dec_Wih    = (const float*)d_in[15];
  const float* dec_Whh    = (const float*)d_in[16];
  const float* dec_b      = (const float*)d_in[17];
  const float* Wout       = (const float*)d_in[18];
  const float* bout       = (const float*)d_in[19];

  char* p = (char*)d_ws;
  auto alloc = [&](size_t sz)->char*{ char* r = p; p += (sz + 255) & ~(size_t)255; return r; };

  // ---- zero zone ----
  unsigned short* Hs     = (unsigned short*)alloc((size_t)1024 * 256 * 2);
  size_t zsz = (size_t)(p - (char*)d_ws);
  // ---- sentinel (0xFF) zone: per-step exchange buffers, write-once ----
  float*          hbufE  = (float*)         alloc((size_t)128 * 4096 * 4);  // [t][b][j]
  float*          hbufD  = (float*)         alloc((size_t)64 * 4096 * 4);
  size_t ffend = (size_t)(p - (char*)d_ws);
  // ---- working buffers (fully written before read) ----
  float*          cfin   = (float*)          alloc(16 * 256 * 4);
  unsigned short* src_bf  = (unsigned short*)alloc((size_t)2048 * 256 * 2);
  unsigned short* tok_bf  = (unsigned short*)alloc((size_t)1024 * 256 * 2);
  unsigned short* wih_bf  = (unsigned short*)alloc((size_t)1024 * 256 * 2);
  unsigned short* wxd_bf  = (unsigned short*)alloc((size_t)1024 * 256 * 2);
  unsigned short* wout_bf = (unsigned short*)alloc((size_t)32000 * 256 * 2);
  unsigned short* whhE_bf = (unsigned short*)alloc((size_t)1024 * 256 * 2);
  unsigned short* whhD_bf = (unsigned short*)alloc((size_t)1024 * 256 * 2);
  float*          Gf      = (float*)         alloc((size_t)1024 * 256 * 4);
  unsigned short* A3bf    = (unsigned short*)alloc((size_t)256 * 256 * 2);
  unsigned short* A2bf    = (unsigned short*)alloc((size_t)1024 * 256 * 2);
  float*          c3f     = (float*)         alloc(256 * 4);
  float*          c4f     = (float*)         alloc(256 * 4);
  float*          c5f     = (float*)         alloc(256);
  float*          xdb     = (float*)         alloc(1024 * 4);
  float*          Xg      = (float*)         alloc((size_t)2048 * 1024 * 4);
  float*          Xd      = (float*)         alloc((size_t)1024 * 1024 * 4);
  unsigned short* enc_bf  = (unsigned short*)alloc((size_t)2048 * 256 * 2);
  unsigned short* KWb     = (unsigned short*)alloc((size_t)2048 * 256 * 2);
  unsigned short* VWWT    = (unsigned short*)alloc((size_t)1024 * 2048 * 2);
  float*          sbf     = (float*)         alloc(2048 * 4);
  if ((size_t)(p - (char*)d_ws) > ws_size) return;

  hipMemsetAsync(d_ws, 0, zsz, stream);
  hipMemsetAsync((char*)d_ws + zsz, 0xFF, ffend - zsz, stream);   // sentinel fill
  hipMemsetAsync(hbufE, 0, 4096 * 4, stream);                     // h_0 = zeros

  // fused prep
  k_prepA<<<3591, 256, 0, stream>>>(input_seq, target_seq, enc_emb, dec_emb,
      enc_Wih, dec_Wih, Wout, enc_Whh, dec_Whh, Wq, Wk, bq, bk, Wo, bo, dec_b,
      src_bf, tok_bf, wih_bf, wxd_bf, wout_bf, whhE_bf, whhD_bf,
      Gf, A3bf, c3f, c4f, c5f, xdb);
  k_prepB<<<516, 256, 0, stream>>>(Gf, Wv, bv, A2bf, xdb);

  // fused Xg + Xd GEMMs
  k_gemmAB<<<192, 256, 0, stream>>>(src_bf, wih_bf, enc_b, Xg, tok_bf, wxd_bf, xdb, Xd);

  // encoder: sentinel-dataflow
  k_enc_g<<<128, 256, 0, stream>>>(whhE_bf, Xg, enc_bf, hbufE, hbufD, cfin);

  // fused post-encoder: KW + VWWT + sb
  k_gemmPost<<<168, 256, 0, stream>>>(enc_bf, A3bf, c3f, KWb, A2bf, VWWT, c4f, c5f, sbf);

  // decoder: one-hop sentinel-dataflow
  k_dec_g<<<128, 256, 0, stream>>>(whhD_bf, Xd, KWb, VWWT, sbf, hbufD, cfin, Hs);

  // logits -> FP32 d_out
  k_gemm<<<dim3(250, 8), 256, 0, stream>>>(Hs, wout_bf, bout, (float*)d_out, nullptr, 1008, 32000);
}